// Round 4
// baseline (1506.816 us; speedup 1.0000x reference)
//
#include <hip/hip_runtime.h>
#include <stdint.h>
#include <stddef.h>

#define N_NODES 24
#define MAX_K   4
#define BATCH   16
#define NODE_ELEMS (BATCH*128*32*32)   /* 2097152 floats = 8 MB */

/* ---------------- numpy RandomState(42) emulation (host side) ---------------- */
namespace nprng {
struct MT { uint32_t key[624]; int pos; };
static void seed_mt(MT& s, uint32_t sd){
  for(int i=0;i<624;i++){ s.key[i]=sd; sd = 1812433253u*(sd^(sd>>30)) + (uint32_t)i + 1u; }
  s.pos = 624;
}
static void gen(MT& s){
  const uint32_t UP=0x80000000u, LOW=0x7fffffffu, MA=0x9908b0dfu;
  uint32_t y; int i;
  for(i=0;i<227;i++){ y=(s.key[i]&UP)|(s.key[i+1]&LOW); s.key[i]=s.key[i+397]^(y>>1)^((y&1u)?MA:0u); }
  for(;i<623;i++){ y=(s.key[i]&UP)|(s.key[i+1]&LOW); s.key[i]=s.key[i-227]^(y>>1)^((y&1u)?MA:0u); }
  y=(s.key[623]&UP)|(s.key[0]&LOW); s.key[623]=s.key[396]^(y>>1)^((y&1u)?MA:0u);
  s.pos=0;
}
static uint32_t next32(MT& s){
  if(s.pos>=624) gen(s);
  uint32_t y=s.key[s.pos++];
  y^=y>>11; y^=(y<<7)&0x9d2c5680u; y^=(y<<15)&0xefc60000u; y^=y>>18;
  return y;
}
static uint64_t next64(MT& s){ uint64_t hi=next32(s); uint64_t lo=next32(s); return (hi<<32)|lo; }
static uint64_t gen_mask(uint64_t r){ r|=r>>1;r|=r>>2;r|=r>>4;r|=r>>8;r|=r>>16;r|=r>>32; return r; }
static long long np_randint(MT& s, long long low, long long high){
  uint64_t rng = (uint64_t)(high - 1 - low);
  if(rng==0) return low;
  uint64_t mask = gen_mask(rng), v;
  if(rng <= 0xffffffffull){ do { v = (uint64_t)next32(s) & mask; } while(v > rng); }
  else                    { do { v = next64(s) & mask; } while(v > rng); }
  return low + (long long)v;
}
static uint64_t np_interval(MT& s, uint64_t mx){
  if(mx==0) return 0;
  uint64_t mask = gen_mask(mx), v;
  if(mx <= 0xffffffffull){ do { v = (uint64_t)next32(s) & mask; } while(v > mx); }
  else                   { do { v = next64(s) & mask; } while(v > mx); }
  return v;
}
} // namespace nprng

/* ---------------- descriptors ---------------- */
struct NodeDesc {
  const float* pred[MAX_K];
  float* outp;
  int k;
  int idx;
};
struct LevelDesc { NodeDesc nd[8]; };
struct PtrList { const float* p[N_NODES]; int n; };

/* ---------------- fused node kernel (nodes >= 1) ----------------
   block: 256 threads, one image row (32 px) of one image, all 128 ch.
   grid: (512, m)  -- 16 images x 32 rows, m nodes per level.
   phase A: gated-agg + relu + depthwise 3x3 straight from global -> ts[128][32]
   phase B: pointwise 128->128 + BN from LDS, weights half-wave-uniform. */
__global__ __launch_bounds__(256)
void k_node(LevelDesc L, const float* __restrict__ aggw, const float* __restrict__ dw,
            const float* __restrict__ pw, const float* __restrict__ gamma,
            const float* __restrict__ beta)
{
  const NodeDesc nd = L.nd[blockIdx.y];
  const int idx = nd.idx, k = nd.k;
  const int row = blockIdx.x & 31, n = blockIdx.x >> 5;
  const int tid = threadIdx.x;
  const int x = tid & 31, g = tid >> 5;          /* 8 channel-groups */

  __shared__ float ts[128][32];                  /* 16 KB */

  const float* agg = aggw + idx * 4;
  const float w0 = 1.0f/(1.0f + __expf(-agg[0]));
  const float w1 = (k>1) ? 1.0f/(1.0f + __expf(-agg[1])) : 0.0f;
  const float w2 = (k>2) ? 1.0f/(1.0f + __expf(-agg[2])) : 0.0f;
  const float w3 = (k>3) ? 1.0f/(1.0f + __expf(-agg[3])) : 0.0f;
  const float* p0 = nd.pred[0];
  const float* p1 = nd.pred[1];
  const float* p2 = nd.pred[2];
  const float* p3 = nd.pred[3];
  const float* dwn = dw + (size_t)(idx - 1) * 9 * 128;

  /* phase A: 16 channels per thread */
#pragma unroll
  for(int cc = 0; cc < 16; ++cc){
    const int c = g*16 + cc;
    const size_t bc = ((size_t)(n*128 + c)) << 10;
    float dwv[9];
#pragma unroll
    for(int q = 0; q < 9; ++q) dwv[q] = dwn[q*128 + c];
    float acc = 0.0f;
#pragma unroll
    for(int ky = 0; ky < 3; ++ky){
      const int iy = row + ky - 1;
      if((unsigned)iy < 32u){                     /* block-uniform branch */
        const size_t br = bc + ((size_t)iy << 5);
#pragma unroll
        for(int kx = 0; kx < 3; ++kx){
          const int ix = x + kx - 1;
          float v = 0.0f;
          if((unsigned)ix < 32u){
            const size_t off = br + ix;
            v = w0 * p0[off];
            if(k > 1) v += w1 * p1[off];
            if(k > 2) v += w2 * p2[off];
            if(k > 3) v += w3 * p3[off];
          }
          v = fmaxf(v, 0.0f);
          acc = fmaf(dwv[ky*3+kx], v, acc);
        }
      }
    }
    ts[c][x] = acc;
  }
  __syncthreads();

  /* phase B: pointwise 128->128 + BN; cout = g*16 .. g*16+15 */
  const float* W = pw + (size_t)(idx - 1) * 128 * 128 + g*16;
  float acc[16];
#pragma unroll
  for(int j = 0; j < 16; ++j) acc[j] = 0.0f;
#pragma unroll 2
  for(int ci = 0; ci < 128; ++ci){
    const float tv = ts[ci][x];
    const float4* w4 = (const float4*)(W + ci*128);
    float4 a = w4[0], b = w4[1], c2 = w4[2], d = w4[3];
    acc[0]+=tv*a.x;  acc[1]+=tv*a.y;  acc[2]+=tv*a.z;  acc[3]+=tv*a.w;
    acc[4]+=tv*b.x;  acc[5]+=tv*b.y;  acc[6]+=tv*b.z;  acc[7]+=tv*b.w;
    acc[8]+=tv*c2.x; acc[9]+=tv*c2.y; acc[10]+=tv*c2.z;acc[11]+=tv*c2.w;
    acc[12]+=tv*d.x; acc[13]+=tv*d.y; acc[14]+=tv*d.z; acc[15]+=tv*d.w;
  }
  const float* gm = gamma + idx*128;
  const float* bt = beta  + idx*128;
  float* op = nd.outp + (((size_t)n*128) << 10) + (row << 5) + x;
#pragma unroll
  for(int j = 0; j < 16; ++j){
    const int co = g*16 + j;
    op[(size_t)co << 10] = acc[j]*gm[co] + bt[co];
  }
}

/* ---------------- fused node-0 kernel (stride-2, CIN=64) ---------------- */
__global__ __launch_bounds__(256)
void k_node0(const float* __restrict__ x_in, const float* __restrict__ aggw,
             const float* __restrict__ dw0, const float* __restrict__ pw0,
             const float* __restrict__ gamma, const float* __restrict__ beta,
             float* __restrict__ outp)
{
  const int row = blockIdx.x & 31, n = blockIdx.x >> 5;
  const int tid = threadIdx.x;
  const int x = tid & 31, g = tid >> 5;

  __shared__ float ts[64][32];                   /* 8 KB */

  const float gate = 1.0f/(1.0f + __expf(-aggw[0]));

  /* phase A: 8 channels per thread; stride-2 SAME (pad_lo=0, pad_hi=1) */
#pragma unroll
  for(int cc = 0; cc < 8; ++cc){
    const int c = g*8 + cc;
    const size_t bc = ((size_t)(n*64 + c)) << 12;
    float dwv[9];
#pragma unroll
    for(int q = 0; q < 9; ++q) dwv[q] = dw0[q*64 + c];
    float acc = 0.0f;
#pragma unroll
    for(int ky = 0; ky < 3; ++ky){
      const int iy = 2*row + ky;
      if(iy < 64){                               /* block-uniform */
        const size_t br = bc + ((size_t)iy << 6);
#pragma unroll
        for(int kx = 0; kx < 3; ++kx){
          const int ix = 2*x + kx;
          float v = 0.0f;
          if(ix < 64) v = gate * x_in[br + ix];
          v = fmaxf(v, 0.0f);
          acc = fmaf(dwv[ky*3+kx], v, acc);
        }
      }
    }
    ts[c][x] = acc;
  }
  __syncthreads();

  /* phase B: pointwise 64->128 + BN */
  const float* W = pw0 + g*16;
  float acc[16];
#pragma unroll
  for(int j = 0; j < 16; ++j) acc[j] = 0.0f;
#pragma unroll 2
  for(int ci = 0; ci < 64; ++ci){
    const float tv = ts[ci][x];
    const float4* w4 = (const float4*)(W + ci*128);
    float4 a = w4[0], b = w4[1], c2 = w4[2], d = w4[3];
    acc[0]+=tv*a.x;  acc[1]+=tv*a.y;  acc[2]+=tv*a.z;  acc[3]+=tv*a.w;
    acc[4]+=tv*b.x;  acc[5]+=tv*b.y;  acc[6]+=tv*b.z;  acc[7]+=tv*b.w;
    acc[8]+=tv*c2.x; acc[9]+=tv*c2.y; acc[10]+=tv*c2.z;acc[11]+=tv*c2.w;
    acc[12]+=tv*d.x; acc[13]+=tv*d.y; acc[14]+=tv*d.z; acc[15]+=tv*d.w;
  }
  float* op = outp + (((size_t)n*128) << 10) + (row << 5) + x;
#pragma unroll
  for(int j = 0; j < 16; ++j){
    const int co = g*16 + j;
    op[(size_t)co << 10] = acc[j]*gamma[co] + beta[co];
  }
}

/* ---------------- final mean over sinks (vectorized) ---------------- */
__global__ __launch_bounds__(256)
void k_mean4(PtrList pl, float scale, float4* __restrict__ out, int n4)
{
  int i = blockIdx.x*256 + threadIdx.x;
  if(i >= n4) return;
  float4 s = make_float4(0.f,0.f,0.f,0.f);
  for(int j = 0; j < pl.n; ++j){
    float4 v = ((const float4*)pl.p[j])[i];
    s.x += v.x; s.y += v.y; s.z += v.z; s.w += v.w;
  }
  s.x *= scale; s.y *= scale; s.z *= scale; s.w *= scale;
  out[i] = s;
}

/* ---------------- host ---------------- */
extern "C" void kernel_launch(void* const* d_in, const int* in_sizes, int n_in,
                              void* d_out, int out_size, void* d_ws, size_t ws_size,
                              hipStream_t stream)
{
  const float* x     = (const float*)d_in[0];
  const float* aggw  = (const float*)d_in[1];
  const float* dw0   = (const float*)d_in[2];
  const float* pw0   = (const float*)d_in[3];
  const float* dw    = (const float*)d_in[4];
  const float* pw    = (const float*)d_in[5];
  const float* gamma = (const float*)d_in[6];
  const float* beta  = (const float*)d_in[7];
  float* out = (float*)d_out;

  /* rebuild the reference's static DAG: np.random.RandomState(42) */
  int preds[N_NODES][MAX_K]; int npred[N_NODES];
  {
    nprng::MT st; nprng::seed_mt(st, 42u);
    npred[0] = 0;
    for(int i = 1; i < N_NODES; ++i){
      int mx = (i < MAX_K) ? i : MAX_K;
      int k = (int)nprng::np_randint(st, 1, (long long)mx + 1);
      int perm[N_NODES];
      for(int q = 0; q < i; ++q) perm[q] = q;
      for(int q = i-1; q >= 1; --q){
        int j = (int)nprng::np_interval(st, (uint64_t)q);
        int tt = perm[q]; perm[q] = perm[j]; perm[j] = tt;
      }
      int tmp[MAX_K];
      for(int a = 0; a < k; ++a) tmp[a] = perm[a];
      for(int a = 1; a < k; ++a){ int v = tmp[a]; int b = a-1;
        while(b >= 0 && tmp[b] > v){ tmp[b+1] = tmp[b]; --b; } tmp[b+1] = v; }
      npred[i] = k;
      for(int a = 0; a < k; ++a) preds[i][a] = tmp[a];
    }
  }

  /* sinks + topological levels */
  int uses[N_NODES]; bool sink[N_NODES];
  for(int i = 0; i < N_NODES; ++i) uses[i] = 0;
  for(int i = 0; i < N_NODES; ++i) for(int q = 0; q < npred[i]; ++q) uses[preds[i][q]]++;
  for(int i = 0; i < N_NODES; ++i) sink[i] = (uses[i] == 0);

  int level[N_NODES]; int maxlev = 0;
  level[0] = 0;
  for(int i = 1; i < N_NODES; ++i){
    int L = 0;
    for(int q = 0; q < npred[i]; ++q){ int l = level[preds[i][q]] + 1; if(l > L) L = l; }
    level[i] = L; if(L > maxlev) maxlev = L;
  }

  /* liveness slot allocation in level order; frees at level boundaries */
  int rem[N_NODES];
  for(int i = 0; i < N_NODES; ++i) rem[i] = uses[i] + (sink[i] ? 1 : 0);
  int slot_of[N_NODES]; bool slot_used[N_NODES]; int nslots = 0;
  for(int i = 0; i < N_NODES; ++i) slot_used[i] = false;
  for(int L = 0; L <= maxlev; ++L){
    for(int i = 0; i < N_NODES; ++i){
      if(level[i] != L) continue;
      int s = -1;
      for(int q = 0; q < nslots; ++q) if(!slot_used[q]){ s = q; break; }
      if(s < 0) s = nslots++;
      slot_used[s] = true; slot_of[i] = s;
    }
    for(int i = 0; i < N_NODES; ++i){
      if(level[i] != L) continue;
      for(int q = 0; q < npred[i]; ++q){
        int p = preds[i][q];
        if(--rem[p] == 0) slot_used[slot_of[p]] = false;
      }
    }
  }

  float* slotbase = (float*)d_ws;
  if(ws_size < (size_t)nslots * NODE_ELEMS * sizeof(float)) return;

  /* level 0: node 0 */
  k_node0<<<dim3(512), dim3(256), 0, stream>>>(x, aggw, dw0, pw0, gamma, beta,
        slotbase + (size_t)slot_of[0]*NODE_ELEMS);

  /* levels 1..maxlev: batch nodes per level (chunks of 8) */
  for(int L = 1; L <= maxlev; ++L){
    int ids[N_NODES]; int cnt = 0;
    for(int i = 0; i < N_NODES; ++i) if(level[i] == L) ids[cnt++] = i;
    for(int off = 0; off < cnt; off += 8){
      int m = (cnt - off < 8) ? (cnt - off) : 8;
      LevelDesc ld;
      for(int j = 0; j < m; ++j){
        int i = ids[off + j];
        NodeDesc& nd = ld.nd[j];
        nd.k = npred[i]; nd.idx = i;
        nd.outp = slotbase + (size_t)slot_of[i]*NODE_ELEMS;
        for(int q = 0; q < MAX_K; ++q){
          int src = preds[i][(q < npred[i]) ? q : 0];
          nd.pred[q] = slotbase + (size_t)slot_of[src]*NODE_ELEMS;
        }
      }
      k_node<<<dim3(512, m), dim3(256), 0, stream>>>(ld, aggw, dw, pw, gamma, beta);
    }
  }

  /* final mean over sinks */
  PtrList pl; pl.n = 0;
  for(int i = 0; i < N_NODES; ++i) if(sink[i]) pl.p[pl.n++] = slotbase + (size_t)slot_of[i]*NODE_ELEMS;
  k_mean4<<<dim3(NODE_ELEMS/4/256), dim3(256), 0, stream>>>(pl, 1.0f/(float)pl.n,
        (float4*)out, NODE_ELEMS/4);
}

// Round 5
// 1278.798 us; speedup vs baseline: 1.1783x; 1.1783x over previous
//
#include <hip/hip_runtime.h>
#include <stdint.h>
#include <stddef.h>

#define N_NODES 24
#define MAX_K   4
#define BATCH   16
#define NODE_ELEMS (BATCH*128*32*32)   /* 2097152 floats = 8 MB */

/* ---------------- numpy RandomState(42) emulation (host side) ---------------- */
namespace nprng {
struct MT { uint32_t key[624]; int pos; };
static void seed_mt(MT& s, uint32_t sd){
  for(int i=0;i<624;i++){ s.key[i]=sd; sd = 1812433253u*(sd^(sd>>30)) + (uint32_t)i + 1u; }
  s.pos = 624;
}
static void gen(MT& s){
  const uint32_t UP=0x80000000u, LOW=0x7fffffffu, MA=0x9908b0dfu;
  uint32_t y; int i;
  for(i=0;i<227;i++){ y=(s.key[i]&UP)|(s.key[i+1]&LOW); s.key[i]=s.key[i+397]^(y>>1)^((y&1u)?MA:0u); }
  for(;i<623;i++){ y=(s.key[i]&UP)|(s.key[i+1]&LOW); s.key[i]=s.key[i-227]^(y>>1)^((y&1u)?MA:0u); }
  y=(s.key[623]&UP)|(s.key[0]&LOW); s.key[623]=s.key[396]^(y>>1)^((y&1u)?MA:0u);
  s.pos=0;
}
static uint32_t next32(MT& s){
  if(s.pos>=624) gen(s);
  uint32_t y=s.key[s.pos++];
  y^=y>>11; y^=(y<<7)&0x9d2c5680u; y^=(y<<15)&0xefc60000u; y^=y>>18;
  return y;
}
static uint64_t next64(MT& s){ uint64_t hi=next32(s); uint64_t lo=next32(s); return (hi<<32)|lo; }
static uint64_t gen_mask(uint64_t r){ r|=r>>1;r|=r>>2;r|=r>>4;r|=r>>8;r|=r>>16;r|=r>>32; return r; }
static long long np_randint(MT& s, long long low, long long high){
  uint64_t rng = (uint64_t)(high - 1 - low);
  if(rng==0) return low;
  uint64_t mask = gen_mask(rng), v;
  if(rng <= 0xffffffffull){ do { v = (uint64_t)next32(s) & mask; } while(v > rng); }
  else                    { do { v = next64(s) & mask; } while(v > rng); }
  return low + (long long)v;
}
static uint64_t np_interval(MT& s, uint64_t mx){
  if(mx==0) return 0;
  uint64_t mask = gen_mask(mx), v;
  if(mx <= 0xffffffffull){ do { v = (uint64_t)next32(s) & mask; } while(v > mx); }
  else                   { do { v = next64(s) & mask; } while(v > mx); }
  return v;
}
} // namespace nprng

/* ---------------- descriptors ---------------- */
struct NodeDesc {
  const float* pred[MAX_K];
  float* outp;
  int k;
  int idx;
};
struct LevelDesc { NodeDesc nd[8]; };
struct PtrList { const float* p[N_NODES]; int n; };

/* XCD pinning: measured round-robin bid%8 -> XCD (learn_hip m09 / T1).
   All kernels map image n to XCD n>>1 so producer writes and consumer
   reads of the same image stay in the same per-XCD L2. */

/* ---------------- fused node kernel (nodes >= 1) ----------------
   block: 256 threads, one image row (32 px), all 128 ch.
   grid: (512, m). bid%8 = XCD p -> images 2p,2p+1.
   phase A: gated-agg + relu + depthwise 3x3 from global (L2-local) -> ts[128][32]
   phase B: pointwise 128->128 + BN from LDS. */
__global__ __launch_bounds__(256)
void k_node(LevelDesc L, const float* __restrict__ aggw, const float* __restrict__ dw,
            const float* __restrict__ pw, const float* __restrict__ gamma,
            const float* __restrict__ beta)
{
  const NodeDesc nd = L.nd[blockIdx.y];
  const int idx = nd.idx, k = nd.k;
  const int p = blockIdx.x & 7;          /* XCD id */
  const int q = blockIdx.x >> 3;         /* 0..63 */
  const int n = (p << 1) + (q >> 5);     /* image */
  const int row = q & 31;
  const int tid = threadIdx.x;
  const int x = tid & 31, g = tid >> 5;  /* 8 channel-groups */

  __shared__ float ts[128][32];          /* 16 KB */

  const float* agg = aggw + idx * 4;
  const float w0 = 1.0f/(1.0f + __expf(-agg[0]));
  const float w1 = (k>1) ? 1.0f/(1.0f + __expf(-agg[1])) : 0.0f;
  const float w2 = (k>2) ? 1.0f/(1.0f + __expf(-agg[2])) : 0.0f;
  const float w3 = (k>3) ? 1.0f/(1.0f + __expf(-agg[3])) : 0.0f;
  const float* p0 = nd.pred[0];
  const float* p1 = nd.pred[1];
  const float* p2 = nd.pred[2];
  const float* p3 = nd.pred[3];
  const float* dwn = dw + (size_t)(idx - 1) * 9 * 128;

  /* phase A: 16 channels per thread */
#pragma unroll
  for(int cc = 0; cc < 16; ++cc){
    const int c = g*16 + cc;
    const size_t bc = ((size_t)(n*128 + c)) << 10;
    float dwv[9];
#pragma unroll
    for(int qq = 0; qq < 9; ++qq) dwv[qq] = dwn[qq*128 + c];
    float acc = 0.0f;
#pragma unroll
    for(int ky = 0; ky < 3; ++ky){
      const int iy = row + ky - 1;
      if((unsigned)iy < 32u){                     /* block-uniform branch */
        const size_t br = bc + ((size_t)iy << 5);
#pragma unroll
        for(int kx = 0; kx < 3; ++kx){
          const int ix = x + kx - 1;
          float v = 0.0f;
          if((unsigned)ix < 32u){
            const size_t off = br + ix;
            v = w0 * p0[off];
            if(k > 1) v += w1 * p1[off];
            if(k > 2) v += w2 * p2[off];
            if(k > 3) v += w3 * p3[off];
          }
          v = fmaxf(v, 0.0f);
          acc = fmaf(dwv[ky*3+kx], v, acc);
        }
      }
    }
    ts[c][x] = acc;
  }
  __syncthreads();

  /* phase B: pointwise 128->128 + BN; cout = g*16 .. g*16+15 */
  const float* W = pw + (size_t)(idx - 1) * 128 * 128 + g*16;
  float acc[16];
#pragma unroll
  for(int j = 0; j < 16; ++j) acc[j] = 0.0f;
#pragma unroll 2
  for(int ci = 0; ci < 128; ++ci){
    const float tv = ts[ci][x];
    const float4* w4 = (const float4*)(W + ci*128);
    float4 a = w4[0], b = w4[1], c2 = w4[2], d = w4[3];
    acc[0]+=tv*a.x;  acc[1]+=tv*a.y;  acc[2]+=tv*a.z;  acc[3]+=tv*a.w;
    acc[4]+=tv*b.x;  acc[5]+=tv*b.y;  acc[6]+=tv*b.z;  acc[7]+=tv*b.w;
    acc[8]+=tv*c2.x; acc[9]+=tv*c2.y; acc[10]+=tv*c2.z;acc[11]+=tv*c2.w;
    acc[12]+=tv*d.x; acc[13]+=tv*d.y; acc[14]+=tv*d.z; acc[15]+=tv*d.w;
  }
  const float* gm = gamma + idx*128;
  const float* bt = beta  + idx*128;
  float* op = nd.outp + (((size_t)n*128) << 10) + (row << 5) + x;
#pragma unroll
  for(int j = 0; j < 16; ++j){
    const int co = g*16 + j;
    op[(size_t)co << 10] = acc[j]*gm[co] + bt[co];
  }
}

/* ---------------- fused node-0 kernel (stride-2, CIN=64) ---------------- */
__global__ __launch_bounds__(256)
void k_node0(const float* __restrict__ x_in, const float* __restrict__ aggw,
             const float* __restrict__ dw0, const float* __restrict__ pw0,
             const float* __restrict__ gamma, const float* __restrict__ beta,
             float* __restrict__ outp)
{
  const int p = blockIdx.x & 7;
  const int q = blockIdx.x >> 3;
  const int n = (p << 1) + (q >> 5);
  const int row = q & 31;
  const int tid = threadIdx.x;
  const int x = tid & 31, g = tid >> 5;

  __shared__ float ts[64][32];                   /* 8 KB */

  const float gate = 1.0f/(1.0f + __expf(-aggw[0]));

  /* phase A: 8 channels per thread; stride-2 SAME (pad_lo=0, pad_hi=1) */
#pragma unroll
  for(int cc = 0; cc < 8; ++cc){
    const int c = g*8 + cc;
    const size_t bc = ((size_t)(n*64 + c)) << 12;
    float dwv[9];
#pragma unroll
    for(int qq = 0; qq < 9; ++qq) dwv[qq] = dw0[qq*64 + c];
    float acc = 0.0f;
#pragma unroll
    for(int ky = 0; ky < 3; ++ky){
      const int iy = 2*row + ky;
      if(iy < 64){                               /* block-uniform */
        const size_t br = bc + ((size_t)iy << 6);
#pragma unroll
        for(int kx = 0; kx < 3; ++kx){
          const int ix = 2*x + kx;
          float v = 0.0f;
          if(ix < 64) v = gate * x_in[br + ix];
          v = fmaxf(v, 0.0f);
          acc = fmaf(dwv[ky*3+kx], v, acc);
        }
      }
    }
    ts[c][x] = acc;
  }
  __syncthreads();

  /* phase B: pointwise 64->128 + BN */
  const float* W = pw0 + g*16;
  float acc[16];
#pragma unroll
  for(int j = 0; j < 16; ++j) acc[j] = 0.0f;
#pragma unroll 2
  for(int ci = 0; ci < 64; ++ci){
    const float tv = ts[ci][x];
    const float4* w4 = (const float4*)(W + ci*128);
    float4 a = w4[0], b = w4[1], c2 = w4[2], d = w4[3];
    acc[0]+=tv*a.x;  acc[1]+=tv*a.y;  acc[2]+=tv*a.z;  acc[3]+=tv*a.w;
    acc[4]+=tv*b.x;  acc[5]+=tv*b.y;  acc[6]+=tv*b.z;  acc[7]+=tv*b.w;
    acc[8]+=tv*c2.x; acc[9]+=tv*c2.y; acc[10]+=tv*c2.z;acc[11]+=tv*c2.w;
    acc[12]+=tv*d.x; acc[13]+=tv*d.y; acc[14]+=tv*d.z; acc[15]+=tv*d.w;
  }
  float* op = outp + (((size_t)n*128) << 10) + (row << 5) + x;
#pragma unroll
  for(int j = 0; j < 16; ++j){
    const int co = g*16 + j;
    op[(size_t)co << 10] = acc[j]*gamma[co] + beta[co];
  }
}

/* ---------------- final mean over sinks (vectorized, XCD-pinned) ---------------- */
__global__ __launch_bounds__(256)
void k_mean4(PtrList pl, float scale, float4* __restrict__ out)
{
  /* grid = 2048 blocks; per image 32768 float4 = 128 blocks */
  const int p = blockIdx.x & 7;
  const int q = blockIdx.x >> 3;          /* 0..255 */
  const int n = (p << 1) + (q >> 7);
  const int j = q & 127;
  const int i4 = n*32768 + j*256 + threadIdx.x;
  float4 s = make_float4(0.f,0.f,0.f,0.f);
  for(int t = 0; t < pl.n; ++t){
    float4 v = ((const float4*)pl.p[t])[i4];
    s.x += v.x; s.y += v.y; s.z += v.z; s.w += v.w;
  }
  s.x *= scale; s.y *= scale; s.z *= scale; s.w *= scale;
  out[i4] = s;
}

/* ---------------- host ---------------- */
extern "C" void kernel_launch(void* const* d_in, const int* in_sizes, int n_in,
                              void* d_out, int out_size, void* d_ws, size_t ws_size,
                              hipStream_t stream)
{
  const float* x     = (const float*)d_in[0];
  const float* aggw  = (const float*)d_in[1];
  const float* dw0   = (const float*)d_in[2];
  const float* pw0   = (const float*)d_in[3];
  const float* dw    = (const float*)d_in[4];
  const float* pw    = (const float*)d_in[5];
  const float* gamma = (const float*)d_in[6];
  const float* beta  = (const float*)d_in[7];
  float* out = (float*)d_out;

  /* rebuild the reference's static DAG: np.random.RandomState(42) */
  int preds[N_NODES][MAX_K]; int npred[N_NODES];
  {
    nprng::MT st; nprng::seed_mt(st, 42u);
    npred[0] = 0;
    for(int i = 1; i < N_NODES; ++i){
      int mx = (i < MAX_K) ? i : MAX_K;
      int k = (int)nprng::np_randint(st, 1, (long long)mx + 1);
      int perm[N_NODES];
      for(int q = 0; q < i; ++q) perm[q] = q;
      for(int q = i-1; q >= 1; --q){
        int j = (int)nprng::np_interval(st, (uint64_t)q);
        int tt = perm[q]; perm[q] = perm[j]; perm[j] = tt;
      }
      int tmp[MAX_K];
      for(int a = 0; a < k; ++a) tmp[a] = perm[a];
      for(int a = 1; a < k; ++a){ int v = tmp[a]; int b = a-1;
        while(b >= 0 && tmp[b] > v){ tmp[b+1] = tmp[b]; --b; } tmp[b+1] = v; }
      npred[i] = k;
      for(int a = 0; a < k; ++a) preds[i][a] = tmp[a];
    }
  }

  /* sinks + topological levels */
  int uses[N_NODES]; bool sink[N_NODES];
  for(int i = 0; i < N_NODES; ++i) uses[i] = 0;
  for(int i = 0; i < N_NODES; ++i) for(int q = 0; q < npred[i]; ++q) uses[preds[i][q]]++;
  for(int i = 0; i < N_NODES; ++i) sink[i] = (uses[i] == 0);

  int level[N_NODES]; int maxlev = 0;
  level[0] = 0;
  for(int i = 1; i < N_NODES; ++i){
    int L = 0;
    for(int q = 0; q < npred[i]; ++q){ int l = level[preds[i][q]] + 1; if(l > L) L = l; }
    level[i] = L; if(L > maxlev) maxlev = L;
  }

  /* liveness slot allocation in level order; frees at level boundaries */
  int rem[N_NODES];
  for(int i = 0; i < N_NODES; ++i) rem[i] = uses[i] + (sink[i] ? 1 : 0);
  int slot_of[N_NODES]; bool slot_used[N_NODES]; int nslots = 0;
  for(int i = 0; i < N_NODES; ++i) slot_used[i] = false;
  for(int L = 0; L <= maxlev; ++L){
    for(int i = 0; i < N_NODES; ++i){
      if(level[i] != L) continue;
      int s = -1;
      for(int q = 0; q < nslots; ++q) if(!slot_used[q]){ s = q; break; }
      if(s < 0) s = nslots++;
      slot_used[s] = true; slot_of[i] = s;
    }
    for(int i = 0; i < N_NODES; ++i){
      if(level[i] != L) continue;
      for(int q = 0; q < npred[i]; ++q){
        int p = preds[i][q];
        if(--rem[p] == 0) slot_used[slot_of[p]] = false;
      }
    }
  }

  float* slotbase = (float*)d_ws;
  if(ws_size < (size_t)nslots * NODE_ELEMS * sizeof(float)) return;

  /* level 0: node 0 */
  k_node0<<<dim3(512), dim3(256), 0, stream>>>(x, aggw, dw0, pw0, gamma, beta,
        slotbase + (size_t)slot_of[0]*NODE_ELEMS);

  /* levels 1..maxlev: batch nodes per level (chunks of 8) */
  for(int L = 1; L <= maxlev; ++L){
    int ids[N_NODES]; int cnt = 0;
    for(int i = 0; i < N_NODES; ++i) if(level[i] == L) ids[cnt++] = i;
    for(int off = 0; off < cnt; off += 8){
      int m = (cnt - off < 8) ? (cnt - off) : 8;
      LevelDesc ld;
      for(int j = 0; j < m; ++j){
        int i = ids[off + j];
        NodeDesc& nd = ld.nd[j];
        nd.k = npred[i]; nd.idx = i;
        nd.outp = slotbase + (size_t)slot_of[i]*NODE_ELEMS;
        for(int q = 0; q < MAX_K; ++q){
          int src = preds[i][(q < npred[i]) ? q : 0];
          nd.pred[q] = slotbase + (size_t)slot_of[src]*NODE_ELEMS;
        }
      }
      k_node<<<dim3(512, m), dim3(256), 0, stream>>>(ld, aggw, dw, pw, gamma, beta);
    }
  }

  /* final mean over sinks */
  PtrList pl; pl.n = 0;
  for(int i = 0; i < N_NODES; ++i) if(sink[i]) pl.p[pl.n++] = slotbase + (size_t)slot_of[i]*NODE_ELEMS;
  k_mean4<<<dim3(2048), dim3(256), 0, stream>>>(pl, 1.0f/(float)pl.n, (float4*)out);
}

// Round 6
// 630.300 us; speedup vs baseline: 2.3906x; 2.0289x over previous
//
#include <hip/hip_runtime.h>
#include <stdint.h>
#include <stddef.h>

#define N_NODES 24
#define MAX_K   4
#define BATCH   16
#define NODE_ELEMS (BATCH*128*32*32)   /* 2097152 floats = 8 MB */

/* ---------------- numpy RandomState(42) emulation (host side) ---------------- */
namespace nprng {
struct MT { uint32_t key[624]; int pos; };
static void seed_mt(MT& s, uint32_t sd){
  for(int i=0;i<624;i++){ s.key[i]=sd; sd = 1812433253u*(sd^(sd>>30)) + (uint32_t)i + 1u; }
  s.pos = 624;
}
static void gen(MT& s){
  const uint32_t UP=0x80000000u, LOW=0x7fffffffu, MA=0x9908b0dfu;
  uint32_t y; int i;
  for(i=0;i<227;i++){ y=(s.key[i]&UP)|(s.key[i+1]&LOW); s.key[i]=s.key[i+397]^(y>>1)^((y&1u)?MA:0u); }
  for(;i<623;i++){ y=(s.key[i]&UP)|(s.key[i+1]&LOW); s.key[i]=s.key[i-227]^(y>>1)^((y&1u)?MA:0u); }
  y=(s.key[623]&UP)|(s.key[0]&LOW); s.key[623]=s.key[396]^(y>>1)^((y&1u)?MA:0u);
  s.pos=0;
}
static uint32_t next32(MT& s){
  if(s.pos>=624) gen(s);
  uint32_t y=s.key[s.pos++];
  y^=y>>11; y^=(y<<7)&0x9d2c5680u; y^=(y<<15)&0xefc60000u; y^=y>>18;
  return y;
}
static uint64_t next64(MT& s){ uint64_t hi=next32(s); uint64_t lo=next32(s); return (hi<<32)|lo; }
static uint64_t gen_mask(uint64_t r){ r|=r>>1;r|=r>>2;r|=r>>4;r|=r>>8;r|=r>>16;r|=r>>32; return r; }
static long long np_randint(MT& s, long long low, long long high){
  uint64_t rng = (uint64_t)(high - 1 - low);
  if(rng==0) return low;
  uint64_t mask = gen_mask(rng), v;
  if(rng <= 0xffffffffull){ do { v = (uint64_t)next32(s) & mask; } while(v > rng); }
  else                    { do { v = next64(s) & mask; } while(v > rng); }
  return low + (long long)v;
}
static uint64_t np_interval(MT& s, uint64_t mx){
  if(mx==0) return 0;
  uint64_t mask = gen_mask(mx), v;
  if(mx <= 0xffffffffull){ do { v = (uint64_t)next32(s) & mask; } while(v > mx); }
  else                   { do { v = next64(s) & mask; } while(v > mx); }
  return v;
}
} // namespace nprng

/* ---------------- descriptors ---------------- */
struct NodeDesc {
  const float* pred[MAX_K];
  float* outp;
  int k;
  int idx;
};
struct PtrList { const float* p[N_NODES]; int n; };

__device__ __forceinline__ float relu_(float v){ return v > 0.0f ? v : 0.0f; }

/* XCD pinning (m09/T1): bid%8 -> XCD; image n lives on XCD n>>1 in every
   kernel, so producer writes and consumer reads stay in the same 4MB L2.
   One node per dispatch keeps per-XCD working set = (k+1) MB (L2-resident). */

/* ---------------- fused node kernel (nodes >= 1) ----------------
   512 threads; block = (img, row). rg=tid&7 -> 4 px; cs=tid>>3 -> 2 ch / 2 cout.
   phase A: gated-agg + relu + depthwise 3x3, float4 global loads -> ts[128][36]
   phase B: pointwise 128->128 + BN; per ci: LDS b128 + float2 weight + 8 FMA. */
__global__ __launch_bounds__(512)
void k_node(NodeDesc nd, const float* __restrict__ aggw, const float* __restrict__ dw,
            const float* __restrict__ pw, const float* __restrict__ gamma,
            const float* __restrict__ beta)
{
  const int idx = nd.idx, k = nd.k;
  const int p = blockIdx.x & 7;
  const int q = blockIdx.x >> 3;
  const int n = (p << 1) + (q >> 5);
  const int row = q & 31;
  const int tid = threadIdx.x;
  const int rg = tid & 7, x4 = rg << 2;
  const int cs = tid >> 3;               /* 0..63 */

  __shared__ __align__(16) float ts[128][36];

  const float* agg = aggw + idx * 4;
  const float w0 = 1.0f/(1.0f + __expf(-agg[0]));
  const float w1 = (k>1) ? 1.0f/(1.0f + __expf(-agg[1])) : 0.0f;
  const float w2 = (k>2) ? 1.0f/(1.0f + __expf(-agg[2])) : 0.0f;
  const float w3 = (k>3) ? 1.0f/(1.0f + __expf(-agg[3])) : 0.0f;
  const float* p0 = nd.pred[0];
  const float* p1 = nd.pred[1];
  const float* p2 = nd.pred[2];
  const float* p3 = nd.pred[3];
  const float* dwn = dw + (size_t)(idx - 1) * 9 * 128;

  /* ---- phase A: 2 channels x 4 px per thread ---- */
#pragma unroll
  for(int cc = 0; cc < 2; ++cc){
    const int c = (cs << 1) + cc;
    const size_t bc = ((size_t)((n << 7) + c)) << 10;
    float dwv[9];
#pragma unroll
    for(int t = 0; t < 9; ++t) dwv[t] = dwn[t*128 + c];
    float a0 = 0.f, a1 = 0.f, a2 = 0.f, a3 = 0.f;
#pragma unroll
    for(int ky = 0; ky < 3; ++ky){
      const int iy = row + ky - 1;
      if((unsigned)iy < 32u){                       /* block-uniform */
        const size_t off = bc + ((size_t)iy << 5) + x4;
        float4 m = *(const float4*)(p0 + off);
        m.x *= w0; m.y *= w0; m.z *= w0; m.w *= w0;
        float l = 0.f, r = 0.f;
        if(rg)     l = w0 * p0[off - 1];
        if(rg < 7) r = w0 * p0[off + 4];
        if(k > 1){
          const float4 v = *(const float4*)(p1 + off);
          m.x = fmaf(w1, v.x, m.x); m.y = fmaf(w1, v.y, m.y);
          m.z = fmaf(w1, v.z, m.z); m.w = fmaf(w1, v.w, m.w);
          if(rg)     l = fmaf(w1, p1[off - 1], l);
          if(rg < 7) r = fmaf(w1, p1[off + 4], r);
        }
        if(k > 2){
          const float4 v = *(const float4*)(p2 + off);
          m.x = fmaf(w2, v.x, m.x); m.y = fmaf(w2, v.y, m.y);
          m.z = fmaf(w2, v.z, m.z); m.w = fmaf(w2, v.w, m.w);
          if(rg)     l = fmaf(w2, p2[off - 1], l);
          if(rg < 7) r = fmaf(w2, p2[off + 4], r);
        }
        if(k > 3){
          const float4 v = *(const float4*)(p3 + off);
          m.x = fmaf(w3, v.x, m.x); m.y = fmaf(w3, v.y, m.y);
          m.z = fmaf(w3, v.z, m.z); m.w = fmaf(w3, v.w, m.w);
          if(rg)     l = fmaf(w3, p3[off - 1], l);
          if(rg < 7) r = fmaf(w3, p3[off + 4], r);
        }
        const float z0 = relu_(l),  z1 = relu_(m.x), z2 = relu_(m.y);
        const float z3 = relu_(m.z), z4 = relu_(m.w), z5 = relu_(r);
        const float d0 = dwv[ky*3], d1 = dwv[ky*3+1], d2 = dwv[ky*3+2];
        a0 = fmaf(d0, z0, fmaf(d1, z1, fmaf(d2, z2, a0)));
        a1 = fmaf(d0, z1, fmaf(d1, z2, fmaf(d2, z3, a1)));
        a2 = fmaf(d0, z2, fmaf(d1, z3, fmaf(d2, z4, a2)));
        a3 = fmaf(d0, z3, fmaf(d1, z4, fmaf(d2, z5, a3)));
      }
    }
    *(float4*)&ts[c][x4] = make_float4(a0, a1, a2, a3);
  }
  __syncthreads();

  /* ---- phase B: 2 cout x 4 px per thread ---- */
  const float* Wp = pw + (size_t)(idx - 1) * 16384 + (cs << 1);
  float acc0=0.f,acc1=0.f,acc2=0.f,acc3=0.f,acc4=0.f,acc5=0.f,acc6=0.f,acc7=0.f;
#pragma unroll 4
  for(int ci = 0; ci < 128; ++ci){
    const float4 tv = *(const float4*)&ts[ci][x4];
    const float2 wv = *(const float2*)(Wp + (ci << 7));
    acc0 = fmaf(wv.x, tv.x, acc0); acc1 = fmaf(wv.x, tv.y, acc1);
    acc2 = fmaf(wv.x, tv.z, acc2); acc3 = fmaf(wv.x, tv.w, acc3);
    acc4 = fmaf(wv.y, tv.x, acc4); acc5 = fmaf(wv.y, tv.y, acc5);
    acc6 = fmaf(wv.y, tv.z, acc6); acc7 = fmaf(wv.y, tv.w, acc7);
  }
  const int co = cs << 1;
  const float g0 = gamma[(idx<<7)+co],   b0 = beta[(idx<<7)+co];
  const float g1 = gamma[(idx<<7)+co+1], b1 = beta[(idx<<7)+co+1];
  float* op = nd.outp + (((size_t)((n << 7) + co)) << 10) + (row << 5) + x4;
  *(float4*)op = make_float4(fmaf(acc0,g0,b0), fmaf(acc1,g0,b0),
                             fmaf(acc2,g0,b0), fmaf(acc3,g0,b0));
  *(float4*)(op + 1024) = make_float4(fmaf(acc4,g1,b1), fmaf(acc5,g1,b1),
                                      fmaf(acc6,g1,b1), fmaf(acc7,g1,b1));
}

/* ---------------- fused node-0 kernel (stride-2, CIN=64) ---------------- */
__global__ __launch_bounds__(512)
void k_node0(const float* __restrict__ x_in, const float* __restrict__ aggw,
             const float* __restrict__ dw0, const float* __restrict__ pw0,
             const float* __restrict__ gamma, const float* __restrict__ beta,
             float* __restrict__ outp)
{
  const int p = blockIdx.x & 7;
  const int q = blockIdx.x >> 3;
  const int n = (p << 1) + (q >> 5);
  const int row = q & 31;
  const int tid = threadIdx.x;
  const int rg = tid & 7, x4 = rg << 2;
  const int cs = tid >> 3;               /* 0..63 = channel */

  __shared__ __align__(16) float ts[64][36];

  const float gate = 1.0f/(1.0f + __expf(-aggw[0]));

  /* ---- phase A: 1 channel x 4 px; stride-2 SAME (pad_lo=0, pad_hi=1) ---- */
  {
    const int c = cs;
    const size_t bc = ((size_t)((n << 6) + c)) << 12;
    float dwv[9];
#pragma unroll
    for(int t = 0; t < 9; ++t) dwv[t] = dw0[t*64 + c];
    float a0 = 0.f, a1 = 0.f, a2 = 0.f, a3 = 0.f;
#pragma unroll
    for(int ky = 0; ky < 3; ++ky){
      const int iy = (row << 1) + ky;
      if(iy < 64){                                  /* block-uniform */
        const size_t off = bc + ((size_t)iy << 6) + (x4 << 1);
        const float4 va = *(const float4*)(x_in + off);
        const float4 vb = *(const float4*)(x_in + off + 4);
        const float ve = (rg < 7) ? x_in[off + 8] : 0.f;
        float z[9];
        z[0]=relu_(gate*va.x); z[1]=relu_(gate*va.y); z[2]=relu_(gate*va.z); z[3]=relu_(gate*va.w);
        z[4]=relu_(gate*vb.x); z[5]=relu_(gate*vb.y); z[6]=relu_(gate*vb.z); z[7]=relu_(gate*vb.w);
        z[8]=relu_(gate*ve);
        const float d0 = dwv[ky*3], d1 = dwv[ky*3+1], d2 = dwv[ky*3+2];
        a0 = fmaf(d0, z[0], fmaf(d1, z[1], fmaf(d2, z[2], a0)));
        a1 = fmaf(d0, z[2], fmaf(d1, z[3], fmaf(d2, z[4], a1)));
        a2 = fmaf(d0, z[4], fmaf(d1, z[5], fmaf(d2, z[6], a2)));
        a3 = fmaf(d0, z[6], fmaf(d1, z[7], fmaf(d2, z[8], a3)));
      }
    }
    *(float4*)&ts[c][x4] = make_float4(a0, a1, a2, a3);
  }
  __syncthreads();

  /* ---- phase B: pointwise 64->128 + BN ---- */
  const float* Wp = pw0 + (cs << 1);
  float acc0=0.f,acc1=0.f,acc2=0.f,acc3=0.f,acc4=0.f,acc5=0.f,acc6=0.f,acc7=0.f;
#pragma unroll 4
  for(int ci = 0; ci < 64; ++ci){
    const float4 tv = *(const float4*)&ts[ci][x4];
    const float2 wv = *(const float2*)(Wp + (ci << 7));
    acc0 = fmaf(wv.x, tv.x, acc0); acc1 = fmaf(wv.x, tv.y, acc1);
    acc2 = fmaf(wv.x, tv.z, acc2); acc3 = fmaf(wv.x, tv.w, acc3);
    acc4 = fmaf(wv.y, tv.x, acc4); acc5 = fmaf(wv.y, tv.y, acc5);
    acc6 = fmaf(wv.y, tv.z, acc6); acc7 = fmaf(wv.y, tv.w, acc7);
  }
  const int co = cs << 1;
  const float g0 = gamma[co],   b0 = beta[co];
  const float g1 = gamma[co+1], b1 = beta[co+1];
  float* op = outp + (((size_t)((n << 7) + co)) << 10) + (row << 5) + x4;
  *(float4*)op = make_float4(fmaf(acc0,g0,b0), fmaf(acc1,g0,b0),
                             fmaf(acc2,g0,b0), fmaf(acc3,g0,b0));
  *(float4*)(op + 1024) = make_float4(fmaf(acc4,g1,b1), fmaf(acc5,g1,b1),
                                      fmaf(acc6,g1,b1), fmaf(acc7,g1,b1));
}

/* ---------------- final mean over sinks (vectorized, XCD-pinned) ---------------- */
__global__ __launch_bounds__(256)
void k_mean4(PtrList pl, float scale, float4* __restrict__ out)
{
  const int p = blockIdx.x & 7;
  const int q = blockIdx.x >> 3;          /* 0..255 */
  const int n = (p << 1) + (q >> 7);
  const int j = q & 127;
  const int i4 = n*32768 + j*256 + threadIdx.x;
  float4 s = make_float4(0.f,0.f,0.f,0.f);
  for(int t = 0; t < pl.n; ++t){
    float4 v = ((const float4*)pl.p[t])[i4];
    s.x += v.x; s.y += v.y; s.z += v.z; s.w += v.w;
  }
  s.x *= scale; s.y *= scale; s.z *= scale; s.w *= scale;
  out[i4] = s;
}

/* ---------------- host ---------------- */
extern "C" void kernel_launch(void* const* d_in, const int* in_sizes, int n_in,
                              void* d_out, int out_size, void* d_ws, size_t ws_size,
                              hipStream_t stream)
{
  const float* x     = (const float*)d_in[0];
  const float* aggw  = (const float*)d_in[1];
  const float* dw0   = (const float*)d_in[2];
  const float* pw0   = (const float*)d_in[3];
  const float* dw    = (const float*)d_in[4];
  const float* pw    = (const float*)d_in[5];
  const float* gamma = (const float*)d_in[6];
  const float* beta  = (const float*)d_in[7];
  float* out = (float*)d_out;

  /* rebuild the reference's static DAG: np.random.RandomState(42) */
  int preds[N_NODES][MAX_K]; int npred[N_NODES];
  {
    nprng::MT st; nprng::seed_mt(st, 42u);
    npred[0] = 0;
    for(int i = 1; i < N_NODES; ++i){
      int mx = (i < MAX_K) ? i : MAX_K;
      int k = (int)nprng::np_randint(st, 1, (long long)mx + 1);
      int perm[N_NODES];
      for(int q = 0; q < i; ++q) perm[q] = q;
      for(int q = i-1; q >= 1; --q){
        int j = (int)nprng::np_interval(st, (uint64_t)q);
        int tt = perm[q]; perm[q] = perm[j]; perm[j] = tt;
      }
      int tmp[MAX_K];
      for(int a = 0; a < k; ++a) tmp[a] = perm[a];
      for(int a = 1; a < k; ++a){ int v = tmp[a]; int b = a-1;
        while(b >= 0 && tmp[b] > v){ tmp[b+1] = tmp[b]; --b; } tmp[b+1] = v; }
      npred[i] = k;
      for(int a = 0; a < k; ++a) preds[i][a] = tmp[a];
    }
  }

  /* sinks + topological levels */
  int uses[N_NODES]; bool sink[N_NODES];
  for(int i = 0; i < N_NODES; ++i) uses[i] = 0;
  for(int i = 0; i < N_NODES; ++i) for(int q = 0; q < npred[i]; ++q) uses[preds[i][q]]++;
  for(int i = 0; i < N_NODES; ++i) sink[i] = (uses[i] == 0);

  int level[N_NODES]; int maxlev = 0;
  level[0] = 0;
  for(int i = 1; i < N_NODES; ++i){
    int L = 0;
    for(int q = 0; q < npred[i]; ++q){ int l = level[preds[i][q]] + 1; if(l > L) L = l; }
    level[i] = L; if(L > maxlev) maxlev = L;
  }

  /* liveness slot allocation in level order; frees at level boundaries */
  int rem[N_NODES];
  for(int i = 0; i < N_NODES; ++i) rem[i] = uses[i] + (sink[i] ? 1 : 0);
  int slot_of[N_NODES]; bool slot_used[N_NODES]; int nslots = 0;
  for(int i = 0; i < N_NODES; ++i) slot_used[i] = false;
  for(int L = 0; L <= maxlev; ++L){
    for(int i = 0; i < N_NODES; ++i){
      if(level[i] != L) continue;
      int s = -1;
      for(int q = 0; q < nslots; ++q) if(!slot_used[q]){ s = q; break; }
      if(s < 0) s = nslots++;
      slot_used[s] = true; slot_of[i] = s;
    }
    for(int i = 0; i < N_NODES; ++i){
      if(level[i] != L) continue;
      for(int q = 0; q < npred[i]; ++q){
        int p = preds[i][q];
        if(--rem[p] == 0) slot_used[slot_of[p]] = false;
      }
    }
  }

  float* slotbase = (float*)d_ws;
  if(ws_size < (size_t)nslots * NODE_ELEMS * sizeof(float)) return;

  /* level 0: node 0 */
  k_node0<<<dim3(512), dim3(512), 0, stream>>>(x, aggw, dw0, pw0, gamma, beta,
        slotbase + (size_t)slot_of[0]*NODE_ELEMS);

  /* levels 1..maxlev: one dispatch per node (L2-residency over batching) */
  for(int L = 1; L <= maxlev; ++L){
    for(int i = 0; i < N_NODES; ++i){
      if(level[i] != L) continue;
      NodeDesc nd;
      nd.k = npred[i]; nd.idx = i;
      nd.outp = slotbase + (size_t)slot_of[i]*NODE_ELEMS;
      for(int q = 0; q < MAX_K; ++q){
        int src = preds[i][(q < npred[i]) ? q : 0];
        nd.pred[q] = slotbase + (size_t)slot_of[src]*NODE_ELEMS;
      }
      k_node<<<dim3(512), dim3(512), 0, stream>>>(nd, aggw, dw, pw, gamma, beta);
    }
  }

  /* final mean over sinks */
  PtrList pl; pl.n = 0;
  for(int i = 0; i < N_NODES; ++i) if(sink[i]) pl.p[pl.n++] = slotbase + (size_t)slot_of[i]*NODE_ELEMS;
  k_mean4<<<dim3(2048), dim3(256), 0, stream>>>(pl, 1.0f/(float)pl.n, (float4*)out);
}

// Round 7
// 616.654 us; speedup vs baseline: 2.4435x; 1.0221x over previous
//
#include <hip/hip_runtime.h>
#include <stdint.h>
#include <stddef.h>

#define N_NODES 24
#define MAX_K   4
#define BATCH   16
#define NODE_ELEMS (BATCH*128*32*32)   /* 2097152 floats = 8 MB */

/* ---------------- numpy RandomState(42) emulation (host side) ---------------- */
namespace nprng {
struct MT { uint32_t key[624]; int pos; };
static void seed_mt(MT& s, uint32_t sd){
  for(int i=0;i<624;i++){ s.key[i]=sd; sd = 1812433253u*(sd^(sd>>30)) + (uint32_t)i + 1u; }
  s.pos = 624;
}
static void gen(MT& s){
  const uint32_t UP=0x80000000u, LOW=0x7fffffffu, MA=0x9908b0dfu;
  uint32_t y; int i;
  for(i=0;i<227;i++){ y=(s.key[i]&UP)|(s.key[i+1]&LOW); s.key[i]=s.key[i+397]^(y>>1)^((y&1u)?MA:0u); }
  for(;i<623;i++){ y=(s.key[i]&UP)|(s.key[i+1]&LOW); s.key[i]=s.key[i-227]^(y>>1)^((y&1u)?MA:0u); }
  y=(s.key[623]&UP)|(s.key[0]&LOW); s.key[623]=s.key[396]^(y>>1)^((y&1u)?MA:0u);
  s.pos=0;
}
static uint32_t next32(MT& s){
  if(s.pos>=624) gen(s);
  uint32_t y=s.key[s.pos++];
  y^=y>>11; y^=(y<<7)&0x9d2c5680u; y^=(y<<15)&0xefc60000u; y^=y>>18;
  return y;
}
static uint64_t next64(MT& s){ uint64_t hi=next32(s); uint64_t lo=next32(s); return (hi<<32)|lo; }
static uint64_t gen_mask(uint64_t r){ r|=r>>1;r|=r>>2;r|=r>>4;r|=r>>8;r|=r>>16;r|=r>>32; return r; }
static long long np_randint(MT& s, long long low, long long high){
  uint64_t rng = (uint64_t)(high - 1 - low);
  if(rng==0) return low;
  uint64_t mask = gen_mask(rng), v;
  if(rng <= 0xffffffffull){ do { v = (uint64_t)next32(s) & mask; } while(v > rng); }
  else                    { do { v = next64(s) & mask; } while(v > rng); }
  return low + (long long)v;
}
static uint64_t np_interval(MT& s, uint64_t mx){
  if(mx==0) return 0;
  uint64_t mask = gen_mask(mx), v;
  if(mx <= 0xffffffffull){ do { v = (uint64_t)next32(s) & mask; } while(v > mx); }
  else                   { do { v = next64(s) & mask; } while(v > mx); }
  return v;
}
} // namespace nprng

/* ---------------- descriptors ---------------- */
struct NodeDesc {
  const float* pred[MAX_K];
  float* outp;
  int k;
  int idx;
};
struct PtrList { const float* p[N_NODES]; int n; };

__device__ __forceinline__ float relu_(float v){ return v > 0.0f ? v : 0.0f; }

/* XCD pinning (m09/T1): bid%8 -> XCD; image n lives on XCD n>>1 in every
   kernel. One node per dispatch keeps per-XCD working set <= ~5MB (L2). */

/* gated aggregation of up to 4 preds for a 6-px window (l, m[4], r) */
__device__ __forceinline__ void agg6(const float* __restrict__ p0, const float* __restrict__ p1,
                                     const float* __restrict__ p2, const float* __restrict__ p3,
                                     int k, float w0, float w1, float w2, float w3,
                                     size_t off, int rg, float z[6])
{
  float4 m = *(const float4*)(p0 + off);
  m.x *= w0; m.y *= w0; m.z *= w0; m.w *= w0;
  float l = 0.f, r = 0.f;
  if(rg)     l = w0 * p0[off - 1];
  if(rg < 7) r = w0 * p0[off + 4];
  if(k > 1){
    const float4 v = *(const float4*)(p1 + off);
    m.x = fmaf(w1, v.x, m.x); m.y = fmaf(w1, v.y, m.y);
    m.z = fmaf(w1, v.z, m.z); m.w = fmaf(w1, v.w, m.w);
    if(rg)     l = fmaf(w1, p1[off - 1], l);
    if(rg < 7) r = fmaf(w1, p1[off + 4], r);
  }
  if(k > 2){
    const float4 v = *(const float4*)(p2 + off);
    m.x = fmaf(w2, v.x, m.x); m.y = fmaf(w2, v.y, m.y);
    m.z = fmaf(w2, v.z, m.z); m.w = fmaf(w2, v.w, m.w);
    if(rg)     l = fmaf(w2, p2[off - 1], l);
    if(rg < 7) r = fmaf(w2, p2[off + 4], r);
  }
  if(k > 3){
    const float4 v = *(const float4*)(p3 + off);
    m.x = fmaf(w3, v.x, m.x); m.y = fmaf(w3, v.y, m.y);
    m.z = fmaf(w3, v.z, m.z); m.w = fmaf(w3, v.w, m.w);
    if(rg)     l = fmaf(w3, p3[off - 1], l);
    if(rg < 7) r = fmaf(w3, p3[off + 4], r);
  }
  z[0] = relu_(l);   z[1] = relu_(m.x); z[2] = relu_(m.y);
  z[3] = relu_(m.z); z[4] = relu_(m.w); z[5] = relu_(r);
}

/* ---------------- fused node kernel (nodes >= 1) ----------------
   512 threads, block = (img, row-pair). grid 256 = 1 block/CU, XCD-pinned.
   phase A: thread = 2 ch x 4 px x BOTH rows; shared halo rows loaded once.
   phase B: thread = 8 cout x 2 px x 1 row; per ci: 8B LDS + 32B W + 16 FMA. */
__global__ __launch_bounds__(512)
void k_node(NodeDesc nd, const float* __restrict__ aggw, const float* __restrict__ dw,
            const float* __restrict__ pw, const float* __restrict__ gamma,
            const float* __restrict__ beta)
{
  const int idx = nd.idx, k = nd.k;
  const int p = blockIdx.x & 7;
  const int q = blockIdx.x >> 3;          /* 0..31 */
  const int n = (p << 1) + (q >> 4);
  const int rp = q & 15;                  /* row pair: rows 2rp, 2rp+1 */
  const int tid = threadIdx.x;

  __shared__ __align__(16) float ts[2][128][36];   /* 36.9 KB */

  const float* agg = aggw + idx * 4;
  const float w0 = 1.0f/(1.0f + __expf(-agg[0]));
  const float w1 = (k>1) ? 1.0f/(1.0f + __expf(-agg[1])) : 0.0f;
  const float w2 = (k>2) ? 1.0f/(1.0f + __expf(-agg[2])) : 0.0f;
  const float w3 = (k>3) ? 1.0f/(1.0f + __expf(-agg[3])) : 0.0f;
  const float* p0 = nd.pred[0];
  const float* p1 = nd.pred[1];
  const float* p2 = nd.pred[2];
  const float* p3 = nd.pred[3];
  const float* dwn = dw + (size_t)(idx - 1) * 9 * 128;

  /* ---- phase A: rg = tid&7 (4px), chg = tid>>3 (0..63) -> 2 ch, both rows ---- */
  {
    const int rg = tid & 7, x4 = rg << 2;
    const int chg = tid >> 3;
    const int r0 = rp << 1;
#pragma unroll
    for(int cc = 0; cc < 2; ++cc){
      const int c = (chg << 1) + cc;
      const size_t bc = ((size_t)((n << 7) + c)) << 10;
      float dwv[9];
#pragma unroll
      for(int t = 0; t < 9; ++t) dwv[t] = dwn[t*128 + c];
      float a0=0.f,a1=0.f,a2=0.f,a3=0.f;     /* row r0   */
      float b0=0.f,b1=0.f,b2=0.f,b3=0.f;     /* row r0+1 */
#pragma unroll
      for(int j = 0; j < 4; ++j){
        const int iy = r0 - 1 + j;
        if((unsigned)iy < 32u){              /* block-uniform */
          float z[6];
          agg6(p0,p1,p2,p3,k,w0,w1,w2,w3, bc + ((size_t)iy<<5) + x4, rg, z);
          if(j < 3){
            const float d0 = dwv[j*3], d1 = dwv[j*3+1], d2 = dwv[j*3+2];
            a0 = fmaf(d0,z[0], fmaf(d1,z[1], fmaf(d2,z[2], a0)));
            a1 = fmaf(d0,z[1], fmaf(d1,z[2], fmaf(d2,z[3], a1)));
            a2 = fmaf(d0,z[2], fmaf(d1,z[3], fmaf(d2,z[4], a2)));
            a3 = fmaf(d0,z[3], fmaf(d1,z[4], fmaf(d2,z[5], a3)));
          }
          if(j > 0){
            const float d0 = dwv[(j-1)*3], d1 = dwv[(j-1)*3+1], d2 = dwv[(j-1)*3+2];
            b0 = fmaf(d0,z[0], fmaf(d1,z[1], fmaf(d2,z[2], b0)));
            b1 = fmaf(d0,z[1], fmaf(d1,z[2], fmaf(d2,z[3], b1)));
            b2 = fmaf(d0,z[2], fmaf(d1,z[3], fmaf(d2,z[4], b2)));
            b3 = fmaf(d0,z[3], fmaf(d1,z[4], fmaf(d2,z[5], b3)));
          }
        }
      }
      *(float4*)&ts[0][c][x4] = make_float4(a0,a1,a2,a3);
      *(float4*)&ts[1][c][x4] = make_float4(b0,b1,b2,b3);
    }
  }
  __syncthreads();

  /* ---- phase B: ro = tid>>8; t = tid&255: rg2 = t&15 (2px), cog = t>>4 (8 couts) ---- */
  const int ro = tid >> 8;
  const int t2 = tid & 255;
  const int rg2 = t2 & 15, px0 = rg2 << 1;
  const int cog = t2 >> 4;                 /* 0..15 -> cout base cog*8 */
  const float* tsr = &ts[ro][0][px0];
  const float* Wp = pw + (size_t)(idx - 1) * 16384 + (cog << 3);
  float2 acc[8];
#pragma unroll
  for(int j = 0; j < 8; ++j) acc[j] = make_float2(0.f, 0.f);
#pragma unroll 4
  for(int ci = 0; ci < 128; ++ci){
    const float2 tv = *(const float2*)(tsr + ci*36);
    const float4 wa = *(const float4*)(Wp + (ci << 7));
    const float4 wb = *(const float4*)(Wp + (ci << 7) + 4);
    acc[0].x = fmaf(wa.x, tv.x, acc[0].x); acc[0].y = fmaf(wa.x, tv.y, acc[0].y);
    acc[1].x = fmaf(wa.y, tv.x, acc[1].x); acc[1].y = fmaf(wa.y, tv.y, acc[1].y);
    acc[2].x = fmaf(wa.z, tv.x, acc[2].x); acc[2].y = fmaf(wa.z, tv.y, acc[2].y);
    acc[3].x = fmaf(wa.w, tv.x, acc[3].x); acc[3].y = fmaf(wa.w, tv.y, acc[3].y);
    acc[4].x = fmaf(wb.x, tv.x, acc[4].x); acc[4].y = fmaf(wb.x, tv.y, acc[4].y);
    acc[5].x = fmaf(wb.y, tv.x, acc[5].x); acc[5].y = fmaf(wb.y, tv.y, acc[5].y);
    acc[6].x = fmaf(wb.z, tv.x, acc[6].x); acc[6].y = fmaf(wb.z, tv.y, acc[6].y);
    acc[7].x = fmaf(wb.w, tv.x, acc[7].x); acc[7].y = fmaf(wb.w, tv.y, acc[7].y);
  }
  const int row = (rp << 1) + ro;
  const int cb = (idx << 7) + (cog << 3);
  float* op = nd.outp + (((size_t)((n << 7) + (cog << 3))) << 10) + (row << 5) + px0;
#pragma unroll
  for(int j = 0; j < 8; ++j){
    const float gm = gamma[cb + j], bt = beta[cb + j];
    *(float2*)(op + ((size_t)j << 10)) =
        make_float2(fmaf(acc[j].x, gm, bt), fmaf(acc[j].y, gm, bt));
  }
}

/* ---------------- fused node-0 kernel (stride-2, CIN=64) ---------------- */
__global__ __launch_bounds__(512)
void k_node0(const float* __restrict__ x_in, const float* __restrict__ aggw,
             const float* __restrict__ dw0, const float* __restrict__ pw0,
             const float* __restrict__ gamma, const float* __restrict__ beta,
             float* __restrict__ outp)
{
  const int p = blockIdx.x & 7;
  const int q = blockIdx.x >> 3;
  const int n = (p << 1) + (q >> 4);
  const int rp = q & 15;
  const int tid = threadIdx.x;

  __shared__ __align__(16) float ts[2][64][36];    /* 18.4 KB */

  const float gate = 1.0f/(1.0f + __expf(-aggw[0]));

  /* ---- phase A: rg = tid&7 (4px), c = tid>>3 (0..63), both rows; stride-2 ---- */
  {
    const int rg = tid & 7, x4 = rg << 2;
    const int c = tid >> 3;
    const int r0 = rp << 1;
    const size_t bc = ((size_t)((n << 6) + c)) << 12;
    float dwv[9];
#pragma unroll
    for(int t = 0; t < 9; ++t) dwv[t] = dw0[t*64 + c];
    float a0=0.f,a1=0.f,a2=0.f,a3=0.f;
    float b0=0.f,b1=0.f,b2=0.f,b3=0.f;
#pragma unroll
    for(int j = 0; j < 5; ++j){              /* input rows 2r0 .. 2r0+4 */
      const int iy = (r0 << 1) + j;
      if(iy < 64){                           /* block-uniform */
        const size_t off = bc + ((size_t)iy << 6) + (x4 << 1);
        const float4 va = *(const float4*)(x_in + off);
        const float4 vb = *(const float4*)(x_in + off + 4);
        const float ve = (rg < 7) ? x_in[off + 8] : 0.f;
        float z[9];
        z[0]=relu_(gate*va.x); z[1]=relu_(gate*va.y); z[2]=relu_(gate*va.z); z[3]=relu_(gate*va.w);
        z[4]=relu_(gate*vb.x); z[5]=relu_(gate*vb.y); z[6]=relu_(gate*vb.z); z[7]=relu_(gate*vb.w);
        z[8]=relu_(gate*ve);
        if(j < 3){                           /* row r0 uses ky = j */
          const float d0 = dwv[j*3], d1 = dwv[j*3+1], d2 = dwv[j*3+2];
          a0 = fmaf(d0,z[0], fmaf(d1,z[1], fmaf(d2,z[2], a0)));
          a1 = fmaf(d0,z[2], fmaf(d1,z[3], fmaf(d2,z[4], a1)));
          a2 = fmaf(d0,z[4], fmaf(d1,z[5], fmaf(d2,z[6], a2)));
          a3 = fmaf(d0,z[6], fmaf(d1,z[7], fmaf(d2,z[8], a3)));
        }
        if(j >= 2){                          /* row r0+1 uses ky = j-2 */
          const float d0 = dwv[(j-2)*3], d1 = dwv[(j-2)*3+1], d2 = dwv[(j-2)*3+2];
          b0 = fmaf(d0,z[0], fmaf(d1,z[1], fmaf(d2,z[2], b0)));
          b1 = fmaf(d0,z[2], fmaf(d1,z[3], fmaf(d2,z[4], b1)));
          b2 = fmaf(d0,z[4], fmaf(d1,z[5], fmaf(d2,z[6], b2)));
          b3 = fmaf(d0,z[6], fmaf(d1,z[7], fmaf(d2,z[8], b3)));
        }
      }
    }
    *(float4*)&ts[0][c][x4] = make_float4(a0,a1,a2,a3);
    *(float4*)&ts[1][c][x4] = make_float4(b0,b1,b2,b3);
  }
  __syncthreads();

  /* ---- phase B: 64 ci -> 128 co; 8 co x 2 px per thread ---- */
  const int ro = tid >> 8;
  const int t2 = tid & 255;
  const int rg2 = t2 & 15, px0 = rg2 << 1;
  const int cog = t2 >> 4;
  const float* tsr = &ts[ro][0][px0];
  const float* Wp = pw0 + (cog << 3);
  float2 acc[8];
#pragma unroll
  for(int j = 0; j < 8; ++j) acc[j] = make_float2(0.f, 0.f);
#pragma unroll 4
  for(int ci = 0; ci < 64; ++ci){
    const float2 tv = *(const float2*)(tsr + ci*36);
    const float4 wa = *(const float4*)(Wp + (ci << 7));
    const float4 wb = *(const float4*)(Wp + (ci << 7) + 4);
    acc[0].x = fmaf(wa.x, tv.x, acc[0].x); acc[0].y = fmaf(wa.x, tv.y, acc[0].y);
    acc[1].x = fmaf(wa.y, tv.x, acc[1].x); acc[1].y = fmaf(wa.y, tv.y, acc[1].y);
    acc[2].x = fmaf(wa.z, tv.x, acc[2].x); acc[2].y = fmaf(wa.z, tv.y, acc[2].y);
    acc[3].x = fmaf(wa.w, tv.x, acc[3].x); acc[3].y = fmaf(wa.w, tv.y, acc[3].y);
    acc[4].x = fmaf(wb.x, tv.x, acc[4].x); acc[4].y = fmaf(wb.x, tv.y, acc[4].y);
    acc[5].x = fmaf(wb.y, tv.x, acc[5].x); acc[5].y = fmaf(wb.y, tv.y, acc[5].y);
    acc[6].x = fmaf(wb.z, tv.x, acc[6].x); acc[6].y = fmaf(wb.z, tv.y, acc[6].y);
    acc[7].x = fmaf(wb.w, tv.x, acc[7].x); acc[7].y = fmaf(wb.w, tv.y, acc[7].y);
  }
  const int row = (rp << 1) + ro;
  float* op = outp + (((size_t)((n << 7) + (cog << 3))) << 10) + (row << 5) + px0;
#pragma unroll
  for(int j = 0; j < 8; ++j){
    const float gm = gamma[(cog << 3) + j], bt = beta[(cog << 3) + j];
    *(float2*)(op + ((size_t)j << 10)) =
        make_float2(fmaf(acc[j].x, gm, bt), fmaf(acc[j].y, gm, bt));
  }
}

/* ---------------- final mean over sinks (vectorized, XCD-pinned) ---------------- */
__global__ __launch_bounds__(256)
void k_mean4(PtrList pl, float scale, float4* __restrict__ out)
{
  const int p = blockIdx.x & 7;
  const int q = blockIdx.x >> 3;          /* 0..255 */
  const int n = (p << 1) + (q >> 7);
  const int j = q & 127;
  const int i4 = n*32768 + j*256 + threadIdx.x;
  float4 s = make_float4(0.f,0.f,0.f,0.f);
  for(int t = 0; t < pl.n; ++t){
    float4 v = ((const float4*)pl.p[t])[i4];
    s.x += v.x; s.y += v.y; s.z += v.z; s.w += v.w;
  }
  s.x *= scale; s.y *= scale; s.z *= scale; s.w *= scale;
  out[i4] = s;
}

/* ---------------- host ---------------- */
extern "C" void kernel_launch(void* const* d_in, const int* in_sizes, int n_in,
                              void* d_out, int out_size, void* d_ws, size_t ws_size,
                              hipStream_t stream)
{
  const float* x     = (const float*)d_in[0];
  const float* aggw  = (const float*)d_in[1];
  const float* dw0   = (const float*)d_in[2];
  const float* pw0   = (const float*)d_in[3];
  const float* dw    = (const float*)d_in[4];
  const float* pw    = (const float*)d_in[5];
  const float* gamma = (const float*)d_in[6];
  const float* beta  = (const float*)d_in[7];
  float* out = (float*)d_out;

  /* rebuild the reference's static DAG: np.random.RandomState(42) */
  int preds[N_NODES][MAX_K]; int npred[N_NODES];
  {
    nprng::MT st; nprng::seed_mt(st, 42u);
    npred[0] = 0;
    for(int i = 1; i < N_NODES; ++i){
      int mx = (i < MAX_K) ? i : MAX_K;
      int k = (int)nprng::np_randint(st, 1, (long long)mx + 1);
      int perm[N_NODES];
      for(int q = 0; q < i; ++q) perm[q] = q;
      for(int q = i-1; q >= 1; --q){
        int j = (int)nprng::np_interval(st, (uint64_t)q);
        int tt = perm[q]; perm[q] = perm[j]; perm[j] = tt;
      }
      int tmp[MAX_K];
      for(int a = 0; a < k; ++a) tmp[a] = perm[a];
      for(int a = 1; a < k; ++a){ int v = tmp[a]; int b = a-1;
        while(b >= 0 && tmp[b] > v){ tmp[b+1] = tmp[b]; --b; } tmp[b+1] = v; }
      npred[i] = k;
      for(int a = 0; a < k; ++a) preds[i][a] = tmp[a];
    }
  }

  /* sinks + topological levels */
  int uses[N_NODES]; bool sink[N_NODES];
  for(int i = 0; i < N_NODES; ++i) uses[i] = 0;
  for(int i = 0; i < N_NODES; ++i) for(int q = 0; q < npred[i]; ++q) uses[preds[i][q]]++;
  for(int i = 0; i < N_NODES; ++i) sink[i] = (uses[i] == 0);

  int level[N_NODES]; int maxlev = 0;
  level[0] = 0;
  for(int i = 1; i < N_NODES; ++i){
    int L = 0;
    for(int q = 0; q < npred[i]; ++q){ int l = level[preds[i][q]] + 1; if(l > L) L = l; }
    level[i] = L; if(L > maxlev) maxlev = L;
  }

  /* liveness slot allocation in level order; frees at level boundaries */
  int rem[N_NODES];
  for(int i = 0; i < N_NODES; ++i) rem[i] = uses[i] + (sink[i] ? 1 : 0);
  int slot_of[N_NODES]; bool slot_used[N_NODES]; int nslots = 0;
  for(int i = 0; i < N_NODES; ++i) slot_used[i] = false;
  for(int L = 0; L <= maxlev; ++L){
    for(int i = 0; i < N_NODES; ++i){
      if(level[i] != L) continue;
      int s = -1;
      for(int q = 0; q < nslots; ++q) if(!slot_used[q]){ s = q; break; }
      if(s < 0) s = nslots++;
      slot_used[s] = true; slot_of[i] = s;
    }
    for(int i = 0; i < N_NODES; ++i){
      if(level[i] != L) continue;
      for(int q = 0; q < npred[i]; ++q){
        int p = preds[i][q];
        if(--rem[p] == 0) slot_used[slot_of[p]] = false;
      }
    }
  }

  float* slotbase = (float*)d_ws;
  if(ws_size < (size_t)nslots * NODE_ELEMS * sizeof(float)) return;

  /* level 0: node 0 */
  k_node0<<<dim3(256), dim3(512), 0, stream>>>(x, aggw, dw0, pw0, gamma, beta,
        slotbase + (size_t)slot_of[0]*NODE_ELEMS);

  /* levels 1..maxlev: one dispatch per node (L2-residency over batching) */
  for(int L = 1; L <= maxlev; ++L){
    for(int i = 0; i < N_NODES; ++i){
      if(level[i] != L) continue;
      NodeDesc nd;
      nd.k = npred[i]; nd.idx = i;
      nd.outp = slotbase + (size_t)slot_of[i]*NODE_ELEMS;
      for(int q = 0; q < MAX_K; ++q){
        int src = preds[i][(q < npred[i]) ? q : 0];
        nd.pred[q] = slotbase + (size_t)slot_of[src]*NODE_ELEMS;
      }
      k_node<<<dim3(256), dim3(512), 0, stream>>>(nd, aggw, dw, pw, gamma, beta);
    }
  }

  /* final mean over sinks */
  PtrList pl; pl.n = 0;
  for(int i = 0; i < N_NODES; ++i) if(sink[i]) pl.p[pl.n++] = slotbase + (size_t)slot_of[i]*NODE_ELEMS;
  k_mean4<<<dim3(2048), dim3(256), 0, stream>>>(pl, 1.0f/(float)pl.n, (float4*)out);
}

// Round 8
// 489.016 us; speedup vs baseline: 3.0813x; 1.2610x over previous
//
#include <hip/hip_runtime.h>
#include <stdint.h>
#include <stddef.h>

#define N_NODES 24
#define MAX_K   4
#define BATCH   16
#define NODE_ELEMS (BATCH*128*32*32)   /* 2097152 floats = 8 MB */

/* ---------------- numpy RandomState(42) emulation (host side) ---------------- */
namespace nprng {
struct MT { uint32_t key[624]; int pos; };
static void seed_mt(MT& s, uint32_t sd){
  for(int i=0;i<624;i++){ s.key[i]=sd; sd = 1812433253u*(sd^(sd>>30)) + (uint32_t)i + 1u; }
  s.pos = 624;
}
static void gen(MT& s){
  const uint32_t UP=0x80000000u, LOW=0x7fffffffu, MA=0x9908b0dfu;
  uint32_t y; int i;
  for(i=0;i<227;i++){ y=(s.key[i]&UP)|(s.key[i+1]&LOW); s.key[i]=s.key[i+397]^(y>>1)^((y&1u)?MA:0u); }
  for(;i<623;i++){ y=(s.key[i]&UP)|(s.key[i+1]&LOW); s.key[i]=s.key[i-227]^(y>>1)^((y&1u)?MA:0u); }
  y=(s.key[623]&UP)|(s.key[0]&LOW); s.key[623]=s.key[396]^(y>>1)^((y&1u)?MA:0u);
  s.pos=0;
}
static uint32_t next32(MT& s){
  if(s.pos>=624) gen(s);
  uint32_t y=s.key[s.pos++];
  y^=y>>11; y^=(y<<7)&0x9d2c5680u; y^=(y<<15)&0xefc60000u; y^=y>>18;
  return y;
}
static uint64_t next64(MT& s){ uint64_t hi=next32(s); uint64_t lo=next32(s); return (hi<<32)|lo; }
static uint64_t gen_mask(uint64_t r){ r|=r>>1;r|=r>>2;r|=r>>4;r|=r>>8;r|=r>>16;r|=r>>32; return r; }
static long long np_randint(MT& s, long long low, long long high){
  uint64_t rng = (uint64_t)(high - 1 - low);
  if(rng==0) return low;
  uint64_t mask = gen_mask(rng), v;
  if(rng <= 0xffffffffull){ do { v = (uint64_t)next32(s) & mask; } while(v > rng); }
  else                    { do { v = next64(s) & mask; } while(v > rng); }
  return low + (long long)v;
}
static uint64_t np_interval(MT& s, uint64_t mx){
  if(mx==0) return 0;
  uint64_t mask = gen_mask(mx), v;
  if(mx <= 0xffffffffull){ do { v = (uint64_t)next32(s) & mask; } while(v > mx); }
  else                   { do { v = next64(s) & mask; } while(v > mx); }
  return v;
}
} // namespace nprng

/* ---------------- descriptors ---------------- */
struct NodeDesc {
  const float* pred[MAX_K];
  float* outp;
  int k;
  int idx;
};
struct PtrList { const float* p[N_NODES]; int n; };

__device__ __forceinline__ float relu_(float v){ return v > 0.0f ? v : 0.0f; }

/* XCD pinning (m09/T1): bid%8 -> XCD; image n lives on XCD n>>1 in every
   kernel. One node per dispatch keeps per-XCD working set <= ~5MB (L2). */

/* gated aggregation of up to 4 preds for a 6-px window (l, m[4], r) */
__device__ __forceinline__ void agg6(const float* __restrict__ p0, const float* __restrict__ p1,
                                     const float* __restrict__ p2, const float* __restrict__ p3,
                                     int k, float w0, float w1, float w2, float w3,
                                     size_t off, int rg, float z[6])
{
  float4 m = *(const float4*)(p0 + off);
  m.x *= w0; m.y *= w0; m.z *= w0; m.w *= w0;
  float l = 0.f, r = 0.f;
  if(rg)     l = w0 * p0[off - 1];
  if(rg < 7) r = w0 * p0[off + 4];
  if(k > 1){
    const float4 v = *(const float4*)(p1 + off);
    m.x = fmaf(w1, v.x, m.x); m.y = fmaf(w1, v.y, m.y);
    m.z = fmaf(w1, v.z, m.z); m.w = fmaf(w1, v.w, m.w);
    if(rg)     l = fmaf(w1, p1[off - 1], l);
    if(rg < 7) r = fmaf(w1, p1[off + 4], r);
  }
  if(k > 2){
    const float4 v = *(const float4*)(p2 + off);
    m.x = fmaf(w2, v.x, m.x); m.y = fmaf(w2, v.y, m.y);
    m.z = fmaf(w2, v.z, m.z); m.w = fmaf(w2, v.w, m.w);
    if(rg)     l = fmaf(w2, p2[off - 1], l);
    if(rg < 7) r = fmaf(w2, p2[off + 4], r);
  }
  if(k > 3){
    const float4 v = *(const float4*)(p3 + off);
    m.x = fmaf(w3, v.x, m.x); m.y = fmaf(w3, v.y, m.y);
    m.z = fmaf(w3, v.z, m.z); m.w = fmaf(w3, v.w, m.w);
    if(rg)     l = fmaf(w3, p3[off - 1], l);
    if(rg < 7) r = fmaf(w3, p3[off + 4], r);
  }
  z[0] = relu_(l);   z[1] = relu_(m.x); z[2] = relu_(m.y);
  z[3] = relu_(m.z); z[4] = relu_(m.w); z[5] = relu_(r);
}

/* ---------------- fused node kernel (nodes >= 1) ----------------
   512 threads, block = (img, row-pair). grid 256 = 1 block/CU, XCD-pinned.
   phase A: thread = 2 ch x 4 px x BOTH rows -> ts[2][128][36].
   phase B: wave w = couts [16w,16w+16), lane = (row, px). Weights are
   WAVE-UNIFORM -> scalar (SGPR) loads, broadcast free; tv via ds_read_b32. */
__global__ __launch_bounds__(512)
void k_node(NodeDesc nd, const float* __restrict__ aggw, const float* __restrict__ dw,
            const float* __restrict__ pw, const float* __restrict__ gamma,
            const float* __restrict__ beta)
{
  const int idx = nd.idx, k = nd.k;
  const int p = blockIdx.x & 7;
  const int q = blockIdx.x >> 3;          /* 0..31 */
  const int n = (p << 1) + (q >> 4);
  const int rp = q & 15;                  /* row pair: rows 2rp, 2rp+1 */
  const int tid = threadIdx.x;

  __shared__ __align__(16) float ts[2][128][36];   /* 36.9 KB */

  const float* agg = aggw + idx * 4;
  const float w0 = 1.0f/(1.0f + __expf(-agg[0]));
  const float w1 = (k>1) ? 1.0f/(1.0f + __expf(-agg[1])) : 0.0f;
  const float w2 = (k>2) ? 1.0f/(1.0f + __expf(-agg[2])) : 0.0f;
  const float w3 = (k>3) ? 1.0f/(1.0f + __expf(-agg[3])) : 0.0f;
  const float* p0 = nd.pred[0];
  const float* p1 = nd.pred[1];
  const float* p2 = nd.pred[2];
  const float* p3 = nd.pred[3];
  const float* dwn = dw + (size_t)(idx - 1) * 9 * 128;

  /* ---- phase A: rg = tid&7 (4px), chg = tid>>3 (0..63) -> 2 ch, both rows ---- */
  {
    const int rg = tid & 7, x4 = rg << 2;
    const int chg = tid >> 3;
    const int r0 = rp << 1;
#pragma unroll
    for(int cc = 0; cc < 2; ++cc){
      const int c = (chg << 1) + cc;
      const size_t bc = ((size_t)((n << 7) + c)) << 10;
      float dwv[9];
#pragma unroll
      for(int t = 0; t < 9; ++t) dwv[t] = dwn[t*128 + c];
      float a0=0.f,a1=0.f,a2=0.f,a3=0.f;     /* row r0   */
      float b0=0.f,b1=0.f,b2=0.f,b3=0.f;     /* row r0+1 */
#pragma unroll
      for(int j = 0; j < 4; ++j){
        const int iy = r0 - 1 + j;
        if((unsigned)iy < 32u){              /* block-uniform */
          float z[6];
          agg6(p0,p1,p2,p3,k,w0,w1,w2,w3, bc + ((size_t)iy<<5) + x4, rg, z);
          if(j < 3){
            const float d0 = dwv[j*3], d1 = dwv[j*3+1], d2 = dwv[j*3+2];
            a0 = fmaf(d0,z[0], fmaf(d1,z[1], fmaf(d2,z[2], a0)));
            a1 = fmaf(d0,z[1], fmaf(d1,z[2], fmaf(d2,z[3], a1)));
            a2 = fmaf(d0,z[2], fmaf(d1,z[3], fmaf(d2,z[4], a2)));
            a3 = fmaf(d0,z[3], fmaf(d1,z[4], fmaf(d2,z[5], a3)));
          }
          if(j > 0){
            const float d0 = dwv[(j-1)*3], d1 = dwv[(j-1)*3+1], d2 = dwv[(j-1)*3+2];
            b0 = fmaf(d0,z[0], fmaf(d1,z[1], fmaf(d2,z[2], b0)));
            b1 = fmaf(d0,z[1], fmaf(d1,z[2], fmaf(d2,z[3], b1)));
            b2 = fmaf(d0,z[2], fmaf(d1,z[3], fmaf(d2,z[4], b2)));
            b3 = fmaf(d0,z[3], fmaf(d1,z[4], fmaf(d2,z[5], b3)));
          }
        }
      }
      *(float4*)&ts[0][c][x4] = make_float4(a0,a1,a2,a3);
      *(float4*)&ts[1][c][x4] = make_float4(b0,b1,b2,b3);
    }
  }
  __syncthreads();

  /* ---- phase B: wave-uniform couts, scalar weight loads ---- */
  const int wv  = __builtin_amdgcn_readfirstlane(tid >> 6);   /* 0..7 */
  const int lane = tid & 63;
  const int ro = lane >> 5, px = lane & 31;
  const float* Wp  = pw + (size_t)(idx - 1) * 16384 + (wv << 4);  /* couts 16wv.. */
  const float* tsr = &ts[ro][0][px];
  float acc[16];
#pragma unroll
  for(int j = 0; j < 16; ++j) acc[j] = 0.f;
#pragma unroll 4
  for(int ci = 0; ci < 128; ++ci){
    const float tv = tsr[ci * 36];             /* ds_read_b32, 2-way alias = free */
    const float* wr = Wp + (ci << 7);          /* wave-uniform -> s_load */
#pragma unroll
    for(int j = 0; j < 16; ++j) acc[j] = fmaf(wr[j], tv, acc[j]);
  }
  const int row = (rp << 1) + ro;
  const int cb = (idx << 7) + (wv << 4);
  float* op = nd.outp + (((size_t)((n << 7) + (wv << 4))) << 10) + (row << 5) + px;
#pragma unroll
  for(int j = 0; j < 16; ++j){
    const float gm = gamma[cb + j], bt = beta[cb + j];   /* uniform -> scalar */
    op[(size_t)j << 10] = fmaf(acc[j], gm, bt);
  }
}

/* ---------------- fused node-0 kernel (stride-2, CIN=64) ---------------- */
__global__ __launch_bounds__(512)
void k_node0(const float* __restrict__ x_in, const float* __restrict__ aggw,
             const float* __restrict__ dw0, const float* __restrict__ pw0,
             const float* __restrict__ gamma, const float* __restrict__ beta,
             float* __restrict__ outp)
{
  const int p = blockIdx.x & 7;
  const int q = blockIdx.x >> 3;
  const int n = (p << 1) + (q >> 4);
  const int rp = q & 15;
  const int tid = threadIdx.x;

  __shared__ __align__(16) float ts[2][64][36];    /* 18.4 KB */

  const float gate = 1.0f/(1.0f + __expf(-aggw[0]));

  /* ---- phase A: rg = tid&7 (4px), c = tid>>3 (0..63), both rows; stride-2 ---- */
  {
    const int rg = tid & 7, x4 = rg << 2;
    const int c = tid >> 3;
    const int r0 = rp << 1;
    const size_t bc = ((size_t)((n << 6) + c)) << 12;
    float dwv[9];
#pragma unroll
    for(int t = 0; t < 9; ++t) dwv[t] = dw0[t*64 + c];
    float a0=0.f,a1=0.f,a2=0.f,a3=0.f;
    float b0=0.f,b1=0.f,b2=0.f,b3=0.f;
#pragma unroll
    for(int j = 0; j < 5; ++j){              /* input rows 2r0 .. 2r0+4 */
      const int iy = (r0 << 1) + j;
      if(iy < 64){                           /* block-uniform */
        const size_t off = bc + ((size_t)iy << 6) + (x4 << 1);
        const float4 va = *(const float4*)(x_in + off);
        const float4 vb = *(const float4*)(x_in + off + 4);
        const float ve = (rg < 7) ? x_in[off + 8] : 0.f;
        float z[9];
        z[0]=relu_(gate*va.x); z[1]=relu_(gate*va.y); z[2]=relu_(gate*va.z); z[3]=relu_(gate*va.w);
        z[4]=relu_(gate*vb.x); z[5]=relu_(gate*vb.y); z[6]=relu_(gate*vb.z); z[7]=relu_(gate*vb.w);
        z[8]=relu_(gate*ve);
        if(j < 3){
          const float d0 = dwv[j*3], d1 = dwv[j*3+1], d2 = dwv[j*3+2];
          a0 = fmaf(d0,z[0], fmaf(d1,z[1], fmaf(d2,z[2], a0)));
          a1 = fmaf(d0,z[2], fmaf(d1,z[3], fmaf(d2,z[4], a1)));
          a2 = fmaf(d0,z[4], fmaf(d1,z[5], fmaf(d2,z[6], a2)));
          a3 = fmaf(d0,z[6], fmaf(d1,z[7], fmaf(d2,z[8], a3)));
        }
        if(j >= 2){
          const float d0 = dwv[(j-2)*3], d1 = dwv[(j-2)*3+1], d2 = dwv[(j-2)*3+2];
          b0 = fmaf(d0,z[0], fmaf(d1,z[1], fmaf(d2,z[2], b0)));
          b1 = fmaf(d0,z[2], fmaf(d1,z[3], fmaf(d2,z[4], b1)));
          b2 = fmaf(d0,z[4], fmaf(d1,z[5], fmaf(d2,z[6], b2)));
          b3 = fmaf(d0,z[6], fmaf(d1,z[7], fmaf(d2,z[8], b3)));
        }
      }
    }
    *(float4*)&ts[0][c][x4] = make_float4(a0,a1,a2,a3);
    *(float4*)&ts[1][c][x4] = make_float4(b0,b1,b2,b3);
  }
  __syncthreads();

  /* ---- phase B: 64 ci -> 128 co; wave-uniform couts, scalar weights ---- */
  const int wv  = __builtin_amdgcn_readfirstlane(tid >> 6);
  const int lane = tid & 63;
  const int ro = lane >> 5, px = lane & 31;
  const float* Wp  = pw0 + (wv << 4);
  const float* tsr = &ts[ro][0][px];
  float acc[16];
#pragma unroll
  for(int j = 0; j < 16; ++j) acc[j] = 0.f;
#pragma unroll 4
  for(int ci = 0; ci < 64; ++ci){
    const float tv = tsr[ci * 36];
    const float* wr = Wp + (ci << 7);
#pragma unroll
    for(int j = 0; j < 16; ++j) acc[j] = fmaf(wr[j], tv, acc[j]);
  }
  const int row = (rp << 1) + ro;
  float* op = outp + (((size_t)((n << 7) + (wv << 4))) << 10) + (row << 5) + px;
#pragma unroll
  for(int j = 0; j < 16; ++j){
    const float gm = gamma[(wv << 4) + j], bt = beta[(wv << 4) + j];
    op[(size_t)j << 10] = fmaf(acc[j], gm, bt);
  }
}

/* ---------------- final mean over sinks (vectorized, XCD-pinned) ---------------- */
__global__ __launch_bounds__(256)
void k_mean4(PtrList pl, float scale, float4* __restrict__ out)
{
  const int p = blockIdx.x & 7;
  const int q = blockIdx.x >> 3;          /* 0..255 */
  const int n = (p << 1) + (q >> 7);
  const int j = q & 127;
  const int i4 = n*32768 + j*256 + threadIdx.x;
  float4 s = make_float4(0.f,0.f,0.f,0.f);
  for(int t = 0; t < pl.n; ++t){
    float4 v = ((const float4*)pl.p[t])[i4];
    s.x += v.x; s.y += v.y; s.z += v.z; s.w += v.w;
  }
  s.x *= scale; s.y *= scale; s.z *= scale; s.w *= scale;
  out[i4] = s;
}

/* ---------------- host ---------------- */
extern "C" void kernel_launch(void* const* d_in, const int* in_sizes, int n_in,
                              void* d_out, int out_size, void* d_ws, size_t ws_size,
                              hipStream_t stream)
{
  const float* x     = (const float*)d_in[0];
  const float* aggw  = (const float*)d_in[1];
  const float* dw0   = (const float*)d_in[2];
  const float* pw0   = (const float*)d_in[3];
  const float* dw    = (const float*)d_in[4];
  const float* pw    = (const float*)d_in[5];
  const float* gamma = (const float*)d_in[6];
  const float* beta  = (const float*)d_in[7];
  float* out = (float*)d_out;

  /* rebuild the reference's static DAG: np.random.RandomState(42) */
  int preds[N_NODES][MAX_K]; int npred[N_NODES];
  {
    nprng::MT st; nprng::seed_mt(st, 42u);
    npred[0] = 0;
    for(int i = 1; i < N_NODES; ++i){
      int mx = (i < MAX_K) ? i : MAX_K;
      int k = (int)nprng::np_randint(st, 1, (long long)mx + 1);
      int perm[N_NODES];
      for(int q = 0; q < i; ++q) perm[q] = q;
      for(int q = i-1; q >= 1; --q){
        int j = (int)nprng::np_interval(st, (uint64_t)q);
        int tt = perm[q]; perm[q] = perm[j]; perm[j] = tt;
      }
      int tmp[MAX_K];
      for(int a = 0; a < k; ++a) tmp[a] = perm[a];
      for(int a = 1; a < k; ++a){ int v = tmp[a]; int b = a-1;
        while(b >= 0 && tmp[b] > v){ tmp[b+1] = tmp[b]; --b; } tmp[b+1] = v; }
      npred[i] = k;
      for(int a = 0; a < k; ++a) preds[i][a] = tmp[a];
    }
  }

  /* sinks + topological levels */
  int uses[N_NODES]; bool sink[N_NODES];
  for(int i = 0; i < N_NODES; ++i) uses[i] = 0;
  for(int i = 0; i < N_NODES; ++i) for(int q = 0; q < npred[i]; ++q) uses[preds[i][q]]++;
  for(int i = 0; i < N_NODES; ++i) sink[i] = (uses[i] == 0);

  int level[N_NODES]; int maxlev = 0;
  level[0] = 0;
  for(int i = 1; i < N_NODES; ++i){
    int L = 0;
    for(int q = 0; q < npred[i]; ++q){ int l = level[preds[i][q]] + 1; if(l > L) L = l; }
    level[i] = L; if(L > maxlev) maxlev = L;
  }

  /* liveness slot allocation in level order; frees at level boundaries */
  int rem[N_NODES];
  for(int i = 0; i < N_NODES; ++i) rem[i] = uses[i] + (sink[i] ? 1 : 0);
  int slot_of[N_NODES]; bool slot_used[N_NODES]; int nslots = 0;
  for(int i = 0; i < N_NODES; ++i) slot_used[i] = false;
  for(int L = 0; L <= maxlev; ++L){
    for(int i = 0; i < N_NODES; ++i){
      if(level[i] != L) continue;
      int s = -1;
      for(int q = 0; q < nslots; ++q) if(!slot_used[q]){ s = q; break; }
      if(s < 0) s = nslots++;
      slot_used[s] = true; slot_of[i] = s;
    }
    for(int i = 0; i < N_NODES; ++i){
      if(level[i] != L) continue;
      for(int q = 0; q < npred[i]; ++q){
        int p = preds[i][q];
        if(--rem[p] == 0) slot_used[slot_of[p]] = false;
      }
    }
  }

  float* slotbase = (float*)d_ws;
  if(ws_size < (size_t)nslots * NODE_ELEMS * sizeof(float)) return;

  /* level 0: node 0 */
  k_node0<<<dim3(256), dim3(512), 0, stream>>>(x, aggw, dw0, pw0, gamma, beta,
        slotbase + (size_t)slot_of[0]*NODE_ELEMS);

  /* levels 1..maxlev: one dispatch per node (L2-residency over batching) */
  for(int L = 1; L <= maxlev; ++L){
    for(int i = 0; i < N_NODES; ++i){
      if(level[i] != L) continue;
      NodeDesc nd;
      nd.k = npred[i]; nd.idx = i;
      nd.outp = slotbase + (size_t)slot_of[i]*NODE_ELEMS;
      for(int q = 0; q < MAX_K; ++q){
        int src = preds[i][(q < npred[i]) ? q : 0];
        nd.pred[q] = slotbase + (size_t)slot_of[src]*NODE_ELEMS;
      }
      k_node<<<dim3(256), dim3(512), 0, stream>>>(nd, aggw, dw, pw, gamma, beta);
    }
  }

  /* final mean over sinks */
  PtrList pl; pl.n = 0;
  for(int i = 0; i < N_NODES; ++i) if(sink[i]) pl.p[pl.n++] = slotbase + (size_t)slot_of[i]*NODE_ELEMS;
  k_mean4<<<dim3(2048), dim3(256), 0, stream>>>(pl, 1.0f/(float)pl.n, (float4*)out);
}

// Round 9
// 292.382 us; speedup vs baseline: 5.1536x; 1.6725x over previous
//
#include <hip/hip_runtime.h>
#include <stdint.h>
#include <stddef.h>

#define N_NODES 24
#define MAX_K   4
#define BATCH   16
#define NODE_ELEMS (BATCH*128*32*32)   /* 2097152 floats = 8 MB */

/* ---------------- numpy RandomState(42) emulation (host side) ---------------- */
namespace nprng {
struct MT { uint32_t key[624]; int pos; };
static void seed_mt(MT& s, uint32_t sd){
  for(int i=0;i<624;i++){ s.key[i]=sd; sd = 1812433253u*(sd^(sd>>30)) + (uint32_t)i + 1u; }
  s.pos = 624;
}
static void gen(MT& s){
  const uint32_t UP=0x80000000u, LOW=0x7fffffffu, MA=0x9908b0dfu;
  uint32_t y; int i;
  for(i=0;i<227;i++){ y=(s.key[i]&UP)|(s.key[i+1]&LOW); s.key[i]=s.key[i+397]^(y>>1)^((y&1u)?MA:0u); }
  for(;i<623;i++){ y=(s.key[i]&UP)|(s.key[i+1]&LOW); s.key[i]=s.key[i-227]^(y>>1)^((y&1u)?MA:0u); }
  y=(s.key[623]&UP)|(s.key[0]&LOW); s.key[623]=s.key[396]^(y>>1)^((y&1u)?MA:0u);
  s.pos=0;
}
static uint32_t next32(MT& s){
  if(s.pos>=624) gen(s);
  uint32_t y=s.key[s.pos++];
  y^=y>>11; y^=(y<<7)&0x9d2c5680u; y^=(y<<15)&0xefc60000u; y^=y>>18;
  return y;
}
static uint64_t next64(MT& s){ uint64_t hi=next32(s); uint64_t lo=next32(s); return (hi<<32)|lo; }
static uint64_t gen_mask(uint64_t r){ r|=r>>1;r|=r>>2;r|=r>>4;r|=r>>8;r|=r>>16;r|=r>>32; return r; }
static long long np_randint(MT& s, long long low, long long high){
  uint64_t rng = (uint64_t)(high - 1 - low);
  if(rng==0) return low;
  uint64_t mask = gen_mask(rng), v;
  if(rng <= 0xffffffffull){ do { v = (uint64_t)next32(s) & mask; } while(v > rng); }
  else                    { do { v = next64(s) & mask; } while(v > rng); }
  return low + (long long)v;
}
static uint64_t np_interval(MT& s, uint64_t mx){
  if(mx==0) return 0;
  uint64_t mask = gen_mask(mx), v;
  if(mx <= 0xffffffffull){ do { v = (uint64_t)next32(s) & mask; } while(v > mx); }
  else                   { do { v = next64(s) & mask; } while(v > mx); }
  return v;
}
} // namespace nprng

/* ---------------- descriptors ---------------- */
struct NodeDesc {
  const float* pred[MAX_K];
  float* outp;
  int k;
  int idx;
};
struct LevelDesc { NodeDesc nd[8]; };
struct PtrList { const float* p[N_NODES]; int n; };

__device__ __forceinline__ float relu_(float v){ return v > 0.0f ? v : 0.0f; }

/* XCD pinning (m09/T1): bid%8 -> XCD; image n lives on XCD n>>1 in every
   kernel. Level batching uses blockIdx.y (x-fastest dispatch order ->
   nodes drain sequentially; <=2 nodes co-resident per CU). */

/* ---------------- fused node kernel (nodes >= 1) ----------------
   512 threads, block = (img, row-pair) x node (y). grid (256, m).
   phase A: thread = 2 ch x 4 px x BOTH rows; halo pixels l/r come from
            neighbor lanes via width-8 shuffles (no extra loads).
   phase B: wave = 16 couts (wave-uniform -> s_load weights), lane=(row,px). */
__global__ __launch_bounds__(512, 4)
void k_node(LevelDesc L, const float* __restrict__ aggw, const float* __restrict__ dw,
            const float* __restrict__ pw, const float* __restrict__ gamma,
            const float* __restrict__ beta)
{
  const NodeDesc nd = L.nd[blockIdx.y];
  const int idx = nd.idx, k = nd.k;
  const int p = blockIdx.x & 7;
  const int q = blockIdx.x >> 3;          /* 0..31 */
  const int n = (p << 1) + (q >> 4);
  const int rp = q & 15;                  /* rows 2rp, 2rp+1 */
  const int tid = threadIdx.x;

  __shared__ __align__(16) float ts[2][128][36];   /* 36 KB */

  const float* agg = aggw + idx * 4;
  const float w0 = 1.0f/(1.0f + __expf(-agg[0]));
  const float w1 = (k>1) ? 1.0f/(1.0f + __expf(-agg[1])) : 0.0f;
  const float w2 = (k>2) ? 1.0f/(1.0f + __expf(-agg[2])) : 0.0f;
  const float w3 = (k>3) ? 1.0f/(1.0f + __expf(-agg[3])) : 0.0f;
  const float* p0 = nd.pred[0];
  const float* p1 = nd.pred[1];
  const float* p2 = nd.pred[2];
  const float* p3 = nd.pred[3];
  const float* dwn = dw + (size_t)(idx - 1) * 9 * 128;

  /* ---- phase A ---- */
  {
    const int rg = tid & 7, x4 = rg << 2;
    const int chg = tid >> 3;
    const int r0 = rp << 1;
#pragma unroll
    for(int cc = 0; cc < 2; ++cc){
      const int c = (chg << 1) + cc;
      const size_t bc = ((size_t)((n << 7) + c)) << 10;
      float dwv[9];
#pragma unroll
      for(int t = 0; t < 9; ++t) dwv[t] = dwn[t*128 + c];
      float a0=0.f,a1=0.f,a2=0.f,a3=0.f;     /* row r0   */
      float b0=0.f,b1=0.f,b2=0.f,b3=0.f;     /* row r0+1 */
#pragma unroll
      for(int j = 0; j < 4; ++j){
        const int iy = r0 - 1 + j;
        if((unsigned)iy < 32u){              /* block-uniform */
          const size_t off = bc + ((size_t)iy << 5) + x4;
          float4 m = *(const float4*)(p0 + off);
          m.x *= w0; m.y *= w0; m.z *= w0; m.w *= w0;
          if(k > 1){
            const float4 v = *(const float4*)(p1 + off);
            m.x = fmaf(w1, v.x, m.x); m.y = fmaf(w1, v.y, m.y);
            m.z = fmaf(w1, v.z, m.z); m.w = fmaf(w1, v.w, m.w);
          }
          if(k > 2){
            const float4 v = *(const float4*)(p2 + off);
            m.x = fmaf(w2, v.x, m.x); m.y = fmaf(w2, v.y, m.y);
            m.z = fmaf(w2, v.z, m.z); m.w = fmaf(w2, v.w, m.w);
          }
          if(k > 3){
            const float4 v = *(const float4*)(p3 + off);
            m.x = fmaf(w3, v.x, m.x); m.y = fmaf(w3, v.y, m.y);
            m.z = fmaf(w3, v.z, m.z); m.w = fmaf(w3, v.w, m.w);
          }
          /* halo from neighbor lanes (width-8 segment = this 32-px row) */
          float l = __shfl_up(m.w, 1, 8);  if(rg == 0) l = 0.f;
          float r = __shfl_down(m.x, 1, 8); if(rg == 7) r = 0.f;
          const float z0 = relu_(l),   z1 = relu_(m.x), z2 = relu_(m.y);
          const float z3 = relu_(m.z), z4 = relu_(m.w), z5 = relu_(r);
          if(j < 3){
            const float d0 = dwv[j*3], d1 = dwv[j*3+1], d2 = dwv[j*3+2];
            a0 = fmaf(d0,z0, fmaf(d1,z1, fmaf(d2,z2, a0)));
            a1 = fmaf(d0,z1, fmaf(d1,z2, fmaf(d2,z3, a1)));
            a2 = fmaf(d0,z2, fmaf(d1,z3, fmaf(d2,z4, a2)));
            a3 = fmaf(d0,z3, fmaf(d1,z4, fmaf(d2,z5, a3)));
          }
          if(j > 0){
            const float d0 = dwv[(j-1)*3], d1 = dwv[(j-1)*3+1], d2 = dwv[(j-1)*3+2];
            b0 = fmaf(d0,z0, fmaf(d1,z1, fmaf(d2,z2, b0)));
            b1 = fmaf(d0,z1, fmaf(d1,z2, fmaf(d2,z3, b1)));
            b2 = fmaf(d0,z2, fmaf(d1,z3, fmaf(d2,z4, b2)));
            b3 = fmaf(d0,z3, fmaf(d1,z4, fmaf(d2,z5, b3)));
          }
        }
      }
      *(float4*)&ts[0][c][x4] = make_float4(a0,a1,a2,a3);
      *(float4*)&ts[1][c][x4] = make_float4(b0,b1,b2,b3);
    }
  }
  __syncthreads();

  /* ---- phase B: wave-uniform couts, scalar weight loads ---- */
  const int wv  = __builtin_amdgcn_readfirstlane(tid >> 6);   /* 0..7 */
  const int lane = tid & 63;
  const int ro = lane >> 5, px = lane & 31;
  const float* Wp  = pw + (size_t)(idx - 1) * 16384 + (wv << 4);
  const float* tsr = &ts[ro][0][px];
  float acc[16];
#pragma unroll
  for(int j = 0; j < 16; ++j) acc[j] = 0.f;
#pragma unroll 4
  for(int ci = 0; ci < 128; ++ci){
    const float tv = tsr[ci * 36];             /* ds_read_b32, 2-way alias = free */
    const float* wr = Wp + (ci << 7);          /* wave-uniform -> s_load */
#pragma unroll
    for(int j = 0; j < 16; ++j) acc[j] = fmaf(wr[j], tv, acc[j]);
  }
  const int row = (rp << 1) + ro;
  const int cb = (idx << 7) + (wv << 4);
  float* op = nd.outp + (((size_t)((n << 7) + (wv << 4))) << 10) + (row << 5) + px;
#pragma unroll
  for(int j = 0; j < 16; ++j){
    const float gm = gamma[cb + j], bt = beta[cb + j];
    op[(size_t)j << 10] = fmaf(acc[j], gm, bt);
  }
}

/* ---------------- fused node-0 kernel (stride-2, CIN=64) ---------------- */
__global__ __launch_bounds__(512, 4)
void k_node0(const float* __restrict__ x_in, const float* __restrict__ aggw,
             const float* __restrict__ dw0, const float* __restrict__ pw0,
             const float* __restrict__ gamma, const float* __restrict__ beta,
             float* __restrict__ outp)
{
  const int p = blockIdx.x & 7;
  const int q = blockIdx.x >> 3;
  const int n = (p << 1) + (q >> 4);
  const int rp = q & 15;
  const int tid = threadIdx.x;

  __shared__ __align__(16) float ts[2][64][36];    /* 18 KB */

  const float gate = 1.0f/(1.0f + __expf(-aggw[0]));

  /* ---- phase A: rg = tid&7 (4px), c = tid>>3, both rows; stride-2 ---- */
  {
    const int rg = tid & 7, x4 = rg << 2;
    const int c = tid >> 3;
    const int r0 = rp << 1;
    const size_t bc = ((size_t)((n << 6) + c)) << 12;
    float dwv[9];
#pragma unroll
    for(int t = 0; t < 9; ++t) dwv[t] = dw0[t*64 + c];
    float a0=0.f,a1=0.f,a2=0.f,a3=0.f;
    float b0=0.f,b1=0.f,b2=0.f,b3=0.f;
#pragma unroll
    for(int j = 0; j < 5; ++j){              /* input rows 2r0 .. 2r0+4 */
      const int iy = (r0 << 1) + j;
      if(iy < 64){                           /* block-uniform */
        const size_t off = bc + ((size_t)iy << 6) + (x4 << 1);
        const float4 va = *(const float4*)(x_in + off);
        const float4 vb = *(const float4*)(x_in + off + 4);
        float ve = __shfl_down(va.x, 1, 8);  /* next lane's first px */
        if(rg == 7) ve = 0.f;
        float z[9];
        z[0]=relu_(gate*va.x); z[1]=relu_(gate*va.y); z[2]=relu_(gate*va.z); z[3]=relu_(gate*va.w);
        z[4]=relu_(gate*vb.x); z[5]=relu_(gate*vb.y); z[6]=relu_(gate*vb.z); z[7]=relu_(gate*vb.w);
        z[8]=relu_(gate*ve);
        if(j < 3){
          const float d0 = dwv[j*3], d1 = dwv[j*3+1], d2 = dwv[j*3+2];
          a0 = fmaf(d0,z[0], fmaf(d1,z[1], fmaf(d2,z[2], a0)));
          a1 = fmaf(d0,z[2], fmaf(d1,z[3], fmaf(d2,z[4], a1)));
          a2 = fmaf(d0,z[4], fmaf(d1,z[5], fmaf(d2,z[6], a2)));
          a3 = fmaf(d0,z[6], fmaf(d1,z[7], fmaf(d2,z[8], a3)));
        }
        if(j >= 2){
          const float d0 = dwv[(j-2)*3], d1 = dwv[(j-2)*3+1], d2 = dwv[(j-2)*3+2];
          b0 = fmaf(d0,z[0], fmaf(d1,z[1], fmaf(d2,z[2], b0)));
          b1 = fmaf(d0,z[2], fmaf(d1,z[3], fmaf(d2,z[4], b1)));
          b2 = fmaf(d0,z[4], fmaf(d1,z[5], fmaf(d2,z[6], b2)));
          b3 = fmaf(d0,z[6], fmaf(d1,z[7], fmaf(d2,z[8], b3)));
        }
      }
    }
    *(float4*)&ts[0][c][x4] = make_float4(a0,a1,a2,a3);
    *(float4*)&ts[1][c][x4] = make_float4(b0,b1,b2,b3);
  }
  __syncthreads();

  /* ---- phase B: 64 ci -> 128 co; wave-uniform couts, scalar weights ---- */
  const int wv  = __builtin_amdgcn_readfirstlane(tid >> 6);
  const int lane = tid & 63;
  const int ro = lane >> 5, px = lane & 31;
  const float* Wp  = pw0 + (wv << 4);
  const float* tsr = &ts[ro][0][px];
  float acc[16];
#pragma unroll
  for(int j = 0; j < 16; ++j) acc[j] = 0.f;
#pragma unroll 4
  for(int ci = 0; ci < 64; ++ci){
    const float tv = tsr[ci * 36];
    const float* wr = Wp + (ci << 7);
#pragma unroll
    for(int j = 0; j < 16; ++j) acc[j] = fmaf(wr[j], tv, acc[j]);
  }
  const int row = (rp << 1) + ro;
  float* op = outp + (((size_t)((n << 7) + (wv << 4))) << 10) + (row << 5) + px;
#pragma unroll
  for(int j = 0; j < 16; ++j){
    const float gm = gamma[(wv << 4) + j], bt = beta[(wv << 4) + j];
    op[(size_t)j << 10] = fmaf(acc[j], gm, bt);
  }
}

/* ---------------- final mean over sinks (vectorized, XCD-pinned) ---------------- */
__global__ __launch_bounds__(256)
void k_mean4(PtrList pl, float scale, float4* __restrict__ out)
{
  const int p = blockIdx.x & 7;
  const int q = blockIdx.x >> 3;          /* 0..255 */
  const int n = (p << 1) + (q >> 7);
  const int j = q & 127;
  const int i4 = n*32768 + j*256 + threadIdx.x;
  float4 s = make_float4(0.f,0.f,0.f,0.f);
  for(int t = 0; t < pl.n; ++t){
    float4 v = ((const float4*)pl.p[t])[i4];
    s.x += v.x; s.y += v.y; s.z += v.z; s.w += v.w;
  }
  s.x *= scale; s.y *= scale; s.z *= scale; s.w *= scale;
  out[i4] = s;
}

/* ---------------- host ---------------- */
extern "C" void kernel_launch(void* const* d_in, const int* in_sizes, int n_in,
                              void* d_out, int out_size, void* d_ws, size_t ws_size,
                              hipStream_t stream)
{
  const float* x     = (const float*)d_in[0];
  const float* aggw  = (const float*)d_in[1];
  const float* dw0   = (const float*)d_in[2];
  const float* pw0   = (const float*)d_in[3];
  const float* dw    = (const float*)d_in[4];
  const float* pw    = (const float*)d_in[5];
  const float* gamma = (const float*)d_in[6];
  const float* beta  = (const float*)d_in[7];
  float* out = (float*)d_out;

  /* rebuild the reference's static DAG: np.random.RandomState(42) */
  int preds[N_NODES][MAX_K]; int npred[N_NODES];
  {
    nprng::MT st; nprng::seed_mt(st, 42u);
    npred[0] = 0;
    for(int i = 1; i < N_NODES; ++i){
      int mx = (i < MAX_K) ? i : MAX_K;
      int k = (int)nprng::np_randint(st, 1, (long long)mx + 1);
      int perm[N_NODES];
      for(int q = 0; q < i; ++q) perm[q] = q;
      for(int q = i-1; q >= 1; --q){
        int j = (int)nprng::np_interval(st, (uint64_t)q);
        int tt = perm[q]; perm[q] = perm[j]; perm[j] = tt;
      }
      int tmp[MAX_K];
      for(int a = 0; a < k; ++a) tmp[a] = perm[a];
      for(int a = 1; a < k; ++a){ int v = tmp[a]; int b = a-1;
        while(b >= 0 && tmp[b] > v){ tmp[b+1] = tmp[b]; --b; } tmp[b+1] = v; }
      npred[i] = k;
      for(int a = 0; a < k; ++a) preds[i][a] = tmp[a];
    }
  }

  /* sinks + topological levels */
  int uses[N_NODES]; bool sink[N_NODES];
  for(int i = 0; i < N_NODES; ++i) uses[i] = 0;
  for(int i = 0; i < N_NODES; ++i) for(int q = 0; q < npred[i]; ++q) uses[preds[i][q]]++;
  for(int i = 0; i < N_NODES; ++i) sink[i] = (uses[i] == 0);

  int level[N_NODES]; int maxlev = 0;
  level[0] = 0;
  for(int i = 1; i < N_NODES; ++i){
    int L = 0;
    for(int q = 0; q < npred[i]; ++q){ int l = level[preds[i][q]] + 1; if(l > L) L = l; }
    level[i] = L; if(L > maxlev) maxlev = L;
  }

  /* liveness slot allocation in level order; frees at level boundaries */
  int rem[N_NODES];
  for(int i = 0; i < N_NODES; ++i) rem[i] = uses[i] + (sink[i] ? 1 : 0);
  int slot_of[N_NODES]; bool slot_used[N_NODES]; int nslots = 0;
  for(int i = 0; i < N_NODES; ++i) slot_used[i] = false;
  for(int L = 0; L <= maxlev; ++L){
    for(int i = 0; i < N_NODES; ++i){
      if(level[i] != L) continue;
      int s = -1;
      for(int q = 0; q < nslots; ++q) if(!slot_used[q]){ s = q; break; }
      if(s < 0) s = nslots++;
      slot_used[s] = true; slot_of[i] = s;
    }
    for(int i = 0; i < N_NODES; ++i){
      if(level[i] != L) continue;
      for(int q = 0; q < npred[i]; ++q){
        int p = preds[i][q];
        if(--rem[p] == 0) slot_used[slot_of[p]] = false;
      }
    }
  }

  float* slotbase = (float*)d_ws;
  if(ws_size < (size_t)nslots * NODE_ELEMS * sizeof(float)) return;

  /* level 0: node 0 */
  k_node0<<<dim3(256), dim3(512), 0, stream>>>(x, aggw, dw0, pw0, gamma, beta,
        slotbase + (size_t)slot_of[0]*NODE_ELEMS);

  /* levels 1..maxlev: one dispatch per level (chunks of 8 nodes) */
  for(int L = 1; L <= maxlev; ++L){
    int ids[N_NODES]; int cnt = 0;
    for(int i = 0; i < N_NODES; ++i) if(level[i] == L) ids[cnt++] = i;
    for(int off = 0; off < cnt; off += 8){
      int m = (cnt - off < 8) ? (cnt - off) : 8;
      LevelDesc ld;
      for(int j = 0; j < m; ++j){
        int i = ids[off + j];
        NodeDesc& nd = ld.nd[j];
        nd.k = npred[i]; nd.idx = i;
        nd.outp = slotbase + (size_t)slot_of[i]*NODE_ELEMS;
        for(int q = 0; q < MAX_K; ++q){
          int src = preds[i][(q < npred[i]) ? q : 0];
          nd.pred[q] = slotbase + (size_t)slot_of[src]*NODE_ELEMS;
        }
      }
      k_node<<<dim3(256, m), dim3(512), 0, stream>>>(ld, aggw, dw, pw, gamma, beta);
    }
  }

  /* final mean over sinks */
  PtrList pl; pl.n = 0;
  for(int i = 0; i < N_NODES; ++i) if(sink[i]) pl.p[pl.n++] = slotbase + (size_t)slot_of[i]*NODE_ELEMS;
  k_mean4<<<dim3(2048), dim3(256), 0, stream>>>(pl, 1.0f/(float)pl.n, (float4*)out);
}